// Round 6
// baseline (258.581 us; speedup 1.0000x reference)
//
#include <hip/hip_runtime.h>

#define D 128
#define SLOT_CAP 64
#define OVF_CAP 4096

typedef __attribute__((ext_vector_type(8))) short short8x;
typedef __attribute__((ext_vector_type(4))) float f32x4;

// ---- bf16 helpers (manual RNE) ----
__device__ inline unsigned int f2bf(float f) {
    unsigned int u = __builtin_bit_cast(unsigned int, f);
    return (u + 0x7fffu + ((u >> 16) & 1u)) >> 16;
}
__device__ inline float bflo(unsigned int v) {
    return __builtin_bit_cast(float, v << 16);
}
__device__ inline float bfhi(unsigned int v) {
    return __builtin_bit_cast(float, v & 0xffff0000u);
}
__device__ inline unsigned int pack2(float lo, float hi) {
    return f2bf(lo) | (f2bf(hi) << 16);
}

// ================= W pre-pack: lane-linear bf16 B fragments =================
__global__ __launch_bounds__(256) void pack_w(
    const float* __restrict__ W1, const float* __restrict__ W2,
    uint4* __restrict__ pack)
{
    int e = blockIdx.x * 256 + threadIdx.x;      // 0..4095
    const float* W = (e & 2048) ? W2 : W1;
    int f = (e >> 6) & 31, l = e & 63;
    int kt = f >> 3, nt = f & 7;
    int k0 = kt * 32 + (l >> 4) * 8;
    int col = nt * 16 + (l & 15);
    unsigned int v[8];
#pragma unroll
    for (int j = 0; j < 8; ++j) v[j] = f2bf(W[(size_t)(k0 + j) * D + col]);
    uint4 o;
    o.x = v[0] | (v[1] << 16);
    o.y = v[2] | (v[3] << 16);
    o.z = v[4] | (v[5] << 16);
    o.w = v[6] | (v[7] << 16);
    pack[e] = o;
}

// ================= MFMA GEMM: out = act(X @ W [+ b]) =================
template <bool IN_BF16, bool RELU, bool OUT_BF16, bool BIAS>
__global__ __launch_bounds__(256) void gemm_mfma(
    const void* __restrict__ xin, const uint4* __restrict__ wpack,
    const float* __restrict__ b, void* __restrict__ xout, int n_rows)
{
    __shared__ uint4 xs4[2048];
    __shared__ uint4 ws4[2048];
    const int t = threadIdx.x;
    const int row0 = blockIdx.x * 128;

#pragma unroll
    for (int i = 0; i < 8; ++i) ws4[t + 256 * i] = wpack[t + 256 * i];

    if (IN_BF16) {
        const uint4* g = (const uint4*)xin;
#pragma unroll
        for (int i = 0; i < 8; ++i) {
            int c = t + 256 * i;
            int row = c >> 4, kc = c & 15;
            int grow = row0 + row;
            if (grow < n_rows)
                xs4[row * 16 + (kc ^ (row & 7))] = g[(size_t)grow * 16 + kc];
        }
    } else {
        const float4* g = (const float4*)xin;
#pragma unroll
        for (int i = 0; i < 8; ++i) {
            int c = t + 256 * i;
            int row = c >> 4, kc = c & 15;
            int grow = row0 + row;
            if (grow < n_rows) {
                float4 f0 = g[(size_t)grow * 32 + kc * 2];
                float4 f1 = g[(size_t)grow * 32 + kc * 2 + 1];
                uint4 v;
                v.x = pack2(f0.x, f0.y);
                v.y = pack2(f0.z, f0.w);
                v.z = pack2(f1.x, f1.y);
                v.w = pack2(f1.z, f1.w);
                xs4[row * 16 + (kc ^ (row & 7))] = v;
            }
        }
    }
    __syncthreads();

    const int l = t & 63;
    const int w = t >> 6;
    const int l15 = l & 15;
    const int lk = l >> 4;

    float bias_v[8];
#pragma unroll
    for (int nt = 0; nt < 8; ++nt) bias_v[nt] = BIAS ? b[nt * 16 + l15] : 0.f;

    f32x4 acc[2][8];
#pragma unroll
    for (int rt = 0; rt < 2; ++rt)
#pragma unroll
        for (int nt = 0; nt < 8; ++nt) acc[rt][nt] = (f32x4){0.f, 0.f, 0.f, 0.f};

    const int arow0 = w * 32 + l15;
    const int arow1 = arow0 + 16;

#pragma unroll
    for (int kt = 0; kt < 4; ++kt) {
        int kc0 = kt * 4 + lk;
        short8x a0 = *(const short8x*)&xs4[arow0 * 16 + (kc0 ^ (arow0 & 7))];
        short8x a1 = *(const short8x*)&xs4[arow1 * 16 + (kc0 ^ (arow1 & 7))];
#pragma unroll
        for (int nt = 0; nt < 8; ++nt) {
            short8x bf = *(const short8x*)&ws4[(kt * 8 + nt) * 64 + l];
            acc[0][nt] = __builtin_amdgcn_mfma_f32_16x16x32_bf16(a0, bf, acc[0][nt], 0, 0, 0);
            acc[1][nt] = __builtin_amdgcn_mfma_f32_16x16x32_bf16(a1, bf, acc[1][nt], 0, 0, 0);
        }
    }

    // D layout: col = l&15, row = (l>>4)*4 + reg   [m89-verified]
#pragma unroll
    for (int rt = 0; rt < 2; ++rt) {
#pragma unroll
        for (int r = 0; r < 4; ++r) {
            int row = row0 + w * 32 + rt * 16 + lk * 4 + r;
            if (row >= n_rows) continue;
#pragma unroll
            for (int nt = 0; nt < 8; ++nt) {
                float v = acc[rt][nt][r] + bias_v[nt];
                if (RELU) v = fmaxf(v, 0.f);
                int col = nt * 16 + l15;
                if (OUT_BF16)
                    ((unsigned short*)xout)[(size_t)row * D + col] = (unsigned short)f2bf(v);
                else
                    ((float*)xout)[(size_t)row * D + col] = v;
            }
        }
    }
}

// ================= slot fill via atomics (4B memory-side writes) ============
// R3 lesson: plain random 4B stores bounce 64B lines cross-XCD (96MB write).
// R1 lesson: atomics write at 4B granularity memory-side. So write slots with
// atomicExch.
__global__ __launch_bounds__(256) void fill_slots(
    const int* __restrict__ esrc, const int* __restrict__ edst,
    int* __restrict__ cnt, int* __restrict__ slots,
    int* __restrict__ ovf_cnt, int2* __restrict__ ovf_list, int E)
{
    int e = blockIdx.x * 256 + threadIdx.x;
    if (e >= E) return;
    int d = edst[e];
    int s = esrc[e];
    int pos = atomicAdd(&cnt[d], 1);
    if (pos < SLOT_CAP) {
        atomicExch(&slots[(size_t)d * SLOT_CAP + pos], s);
    } else {
        int o = atomicAdd(ovf_cnt, 1);
        if (o < OVF_CAP) ovf_list[o] = make_int2(s, d);
    }
}

// ================= pull: out[n] = sum_{slots} z[src] + b2  (f32 out) ========
// 32 lanes per node (lane -> cols 4l..4l+3), 8 nodes per 256-thread block.
// Slot reads sequential (4B/edge, full-line use); z-row gather is the BW cost.
__global__ __launch_bounds__(256) void pull_slots(
    const uint2* __restrict__ z2, const int* __restrict__ slots,
    const int* __restrict__ cnt, const float* __restrict__ b2,
    float* __restrict__ out, int n_nodes)
{
    int node = blockIdx.x * 8 + (threadIdx.x >> 5);
    int lane = threadIdx.x & 31;
    if (node >= n_nodes) return;
    int deg = cnt[node];
    if (deg > SLOT_CAP) deg = SLOT_CAP;
    const int* sl = slots + (size_t)node * SLOT_CAP;

    float a0 = 0.f, a1 = 0.f, a2 = 0.f, a3 = 0.f;
    int i = 0;
    for (; i + 4 <= deg; i += 4) {
        int4 s = *(const int4*)(sl + i);     // 4 independent row gathers in flight
        uint2 v0 = z2[(size_t)s.x * 32 + lane];
        uint2 v1 = z2[(size_t)s.y * 32 + lane];
        uint2 v2 = z2[(size_t)s.z * 32 + lane];
        uint2 v3 = z2[(size_t)s.w * 32 + lane];
        a0 += bflo(v0.x) + bflo(v1.x) + bflo(v2.x) + bflo(v3.x);
        a1 += bfhi(v0.x) + bfhi(v1.x) + bfhi(v2.x) + bfhi(v3.x);
        a2 += bflo(v0.y) + bflo(v1.y) + bflo(v2.y) + bflo(v3.y);
        a3 += bfhi(v0.y) + bfhi(v1.y) + bfhi(v2.y) + bfhi(v3.y);
    }
    for (; i < deg; ++i) {
        int s = sl[i];
        uint2 v = z2[(size_t)s * 32 + lane];
        a0 += bflo(v.x); a1 += bfhi(v.x);
        a2 += bflo(v.y); a3 += bfhi(v.y);
    }
    float4 bv = ((const float4*)b2)[lane];
    float4 o = make_float4(a0 + bv.x, a1 + bv.y, a2 + bv.z, a3 + bv.w);
    ((float4*)out)[(size_t)node * 32 + lane] = o;
}

// Rare overflow edges: out[d] += z[s] (f32 atomics; b2 already added in pull).
__global__ __launch_bounds__(32) void ovf_f32(
    const int* __restrict__ ovf_cnt, const int2* __restrict__ ovf_list,
    const uint2* __restrict__ z2, float* __restrict__ out)
{
    int n = *ovf_cnt;
    if (n > OVF_CAP) n = OVF_CAP;
    int lane = threadIdx.x;  // 32
    for (int i = 0; i < n; ++i) {
        int2 sd = ovf_list[i];
        uint2 v = z2[(size_t)sd.x * 32 + lane];
        unsafeAtomicAdd(&out[(size_t)sd.y * D + lane * 4 + 0], bflo(v.x));
        unsafeAtomicAdd(&out[(size_t)sd.y * D + lane * 4 + 1], bfhi(v.x));
        unsafeAtomicAdd(&out[(size_t)sd.y * D + lane * 4 + 2], bflo(v.y));
        unsafeAtomicAdd(&out[(size_t)sd.y * D + lane * 4 + 3], bfhi(v.y));
    }
}

// ================= fallback path (f32 atomic scatter) =================
template <bool RELU>
__global__ __launch_bounds__(256) void gemm_bias_act(
    const float* xin, const float* __restrict__ W,
    const float* __restrict__ b, float* xout, int n_rows)
{
    __shared__ float Ws[D * D];
    __shared__ float xs[32 * D];
    const int t = threadIdx.x;
    const int row0 = blockIdx.x * 32;
    const float4* Wv = (const float4*)W;
    float4* Wsv = (float4*)Ws;
#pragma unroll
    for (int i = 0; i < 16; ++i) Wsv[t + 256 * i] = Wv[t + 256 * i];
    const float4* xv = (const float4*)xin;
    float4* xsv = (float4*)xs;
#pragma unroll
    for (int i = 0; i < 4; ++i) {
        int f4 = t + 256 * i;
        int row = row0 + (f4 >> 5);
        if (row < n_rows) xsv[f4] = xv[(size_t)row0 * 32 + f4];
    }
    __syncthreads();
    const int cg = t & 31;
    const int rg = t >> 5;
    float4 bias = ((const float4*)b)[cg];
    float4 acc[4];
#pragma unroll
    for (int ri = 0; ri < 4; ++ri) acc[ri] = make_float4(0.f, 0.f, 0.f, 0.f);
#pragma unroll 4
    for (int k = 0; k < D; k += 4) {
        float4 w0 = Wsv[(k + 0) * 32 + cg];
        float4 w1 = Wsv[(k + 1) * 32 + cg];
        float4 w2 = Wsv[(k + 2) * 32 + cg];
        float4 w3 = Wsv[(k + 3) * 32 + cg];
#pragma unroll
        for (int ri = 0; ri < 4; ++ri) {
            float4 xa = xsv[(rg + 8 * ri) * 32 + (k >> 2)];
            acc[ri].x = fmaf(xa.x, w0.x, fmaf(xa.y, w1.x, fmaf(xa.z, w2.x, fmaf(xa.w, w3.x, acc[ri].x))));
            acc[ri].y = fmaf(xa.x, w0.y, fmaf(xa.y, w1.y, fmaf(xa.z, w2.y, fmaf(xa.w, w3.y, acc[ri].y))));
            acc[ri].z = fmaf(xa.x, w0.z, fmaf(xa.y, w1.z, fmaf(xa.z, w2.z, fmaf(xa.w, w3.z, acc[ri].z))));
            acc[ri].w = fmaf(xa.x, w0.w, fmaf(xa.y, w1.w, fmaf(xa.z, w2.w, fmaf(xa.w, w3.w, acc[ri].w))));
        }
    }
#pragma unroll
    for (int ri = 0; ri < 4; ++ri) {
        int row = row0 + rg + 8 * ri;
        if (row >= n_rows) continue;
        float4 o;
        o.x = acc[ri].x + bias.x; o.y = acc[ri].y + bias.y;
        o.z = acc[ri].z + bias.z; o.w = acc[ri].w + bias.w;
        if (RELU) {
            o.x = fmaxf(o.x, 0.f); o.y = fmaxf(o.y, 0.f);
            o.z = fmaxf(o.z, 0.f); o.w = fmaxf(o.w, 0.f);
        }
        ((float4*)xout)[(size_t)row * 32 + cg] = o;
    }
}

__global__ __launch_bounds__(256) void zero_kernel(float4* p, int n4)
{
    int i = blockIdx.x * 256 + threadIdx.x;
    int stride = gridDim.x * 256;
    for (; i < n4; i += stride) p[i] = make_float4(0.f, 0.f, 0.f, 0.f);
}

__global__ __launch_bounds__(256) void scatter_kernel(
    const float* __restrict__ h, const int* __restrict__ esrc,
    const int* __restrict__ edst, float* __restrict__ agg, long n_items)
{
    long idx = (long)blockIdx.x * 256 + threadIdx.x;
    long stride = (long)gridDim.x * 256;
    for (; idx < n_items; idx += stride) {
        int e = (int)(idx >> 7);
        int c = (int)(idx & 127);
        int s = esrc[e];
        int d = edst[e];
        unsafeAtomicAdd(&agg[(size_t)d * D + c], h[(size_t)s * D + c]);
    }
}

extern "C" void kernel_launch(void* const* d_in, const int* in_sizes, int n_in,
                              void* d_out, int out_size, void* d_ws, size_t ws_size,
                              hipStream_t stream)
{
    const float* x    = (const float*)d_in[0];
    const int*   esrc = (const int*)d_in[1];
    const int*   edst = (const int*)d_in[2];
    const float* W1   = (const float*)d_in[3];
    const float* b1   = (const float*)d_in[4];
    const float* W2   = (const float*)d_in[5];
    const float* b2   = (const float*)d_in[6];
    float* out = (float*)d_out;

    const int N = in_sizes[0] / D;   // 100000
    const int E = in_sizes[1];       // 1600000

    char* ws = (char*)d_ws;
    size_t off_h     = 0;
    size_t off_z     = off_h + (size_t)N * 256;                 // h2: 25.6 MB
    size_t off_slots = off_z + (size_t)N * 256;                 // z2: 25.6 MB
    size_t off_cnt   = off_slots + (size_t)N * SLOT_CAP * 4;    // slots: 25.6 MB
    size_t off_pack  = (off_cnt + (size_t)N * 4 + 255) & ~(size_t)255;
    size_t off_ovfc  = off_pack + 65536;
    size_t off_ovfl  = off_ovfc + 16;
    size_t need      = off_ovfl + (size_t)OVF_CAP * 8;

    const int nblk = (N + 127) / 128;   // 782

    if (ws_size >= need) {
        uint2* h2       = (uint2*)(ws + off_h);
        uint2* z2       = (uint2*)(ws + off_z);
        int*   slots    = (int*)(ws + off_slots);
        int*   cnt      = (int*)(ws + off_cnt);
        uint4* pack     = (uint4*)(ws + off_pack);
        int*   ovf_cnt  = (int*)(ws + off_ovfc);
        int2*  ovf_list = (int2*)(ws + off_ovfl);

        hipMemsetAsync(cnt, 0, (size_t)N * 4, stream);
        hipMemsetAsync(ovf_cnt, 0, 16, stream);

        // 0) pack W1,W2 into lane-linear bf16 B-fragments
        pack_w<<<16, 256, 0, stream>>>(W1, W2, pack);

        // 1) CSR slots (atomic 4B writes — no line bouncing)
        fill_slots<<<(E + 255) / 256, 256, 0, stream>>>(
            esrc, edst, cnt, slots, ovf_cnt, ovf_list, E);

        // 2) h = relu(x @ W1 + b1), bf16
        gemm_mfma<false, true, true, true><<<nblk, 256, 0, stream>>>(x, pack, b1, h2, N);

        // 3) z = h @ W2 (no bias), bf16   [agg@W2+b2 == segsum(h@W2)+b2]
        gemm_mfma<true, false, true, false><<<nblk, 256, 0, stream>>>(h2, pack + 2048, nullptr, z2, N);

        // 4) out[n] = sum z[src in slots] + b2, f32
        pull_slots<<<(N + 7) / 8, 256, 0, stream>>>(z2, slots, cnt, b2, out, N);

        // 5) rare overflow edges
        ovf_f32<<<1, 32, 0, stream>>>(ovf_cnt, ovf_list, z2, out);
    } else {
        float* h = (float*)ws;
        const int nb32 = (N + 31) / 32;
        gemm_bias_act<true><<<nb32, 256, 0, stream>>>(x, W1, b1, h, N);
        zero_kernel<<<2048, 256, 0, stream>>>((float4*)out, N * D / 4);
        scatter_kernel<<<8192, 256, 0, stream>>>(h, esrc, edst, out, (long)E * D);
        gemm_bias_act<false><<<nb32, 256, 0, stream>>>(out, W2, b2, out, N);
    }
}

// Round 7
// 195.124 us; speedup vs baseline: 1.3252x; 1.3252x over previous
//
#include <hip/hip_runtime.h>

#define D 128
#define NPB 256            // nodes per bucket (dst>>8)
#define NBMAX 512          // max buckets supported (N <= 131072)
#define BCAP 6144          // LDS srclist capacity per bucket (mean 4096, +45 sigma)
#define CHUNK 8192         // edges per workgroup in hist/scatter

typedef __attribute__((ext_vector_type(8))) short short8x;
typedef __attribute__((ext_vector_type(4))) float f32x4;

// ---- bf16 helpers (manual RNE) ----
__device__ inline unsigned int f2bf(float f) {
    unsigned int u = __builtin_bit_cast(unsigned int, f);
    return (u + 0x7fffu + ((u >> 16) & 1u)) >> 16;
}
__device__ inline float bflo(unsigned int v) {
    return __builtin_bit_cast(float, v << 16);
}
__device__ inline float bfhi(unsigned int v) {
    return __builtin_bit_cast(float, v & 0xffff0000u);
}
__device__ inline unsigned int pack2(float lo, float hi) {
    return f2bf(lo) | (f2bf(hi) << 16);
}

// ================= W pre-pack: lane-linear bf16 B fragments =================
__global__ __launch_bounds__(256) void pack_w(
    const float* __restrict__ W1, const float* __restrict__ W2,
    uint4* __restrict__ pack)
{
    int e = blockIdx.x * 256 + threadIdx.x;      // 0..4095
    const float* W = (e & 2048) ? W2 : W1;
    int f = (e >> 6) & 31, l = e & 63;
    int kt = f >> 3, nt = f & 7;
    int k0 = kt * 32 + (l >> 4) * 8;
    int col = nt * 16 + (l & 15);
    unsigned int v[8];
#pragma unroll
    for (int j = 0; j < 8; ++j) v[j] = f2bf(W[(size_t)(k0 + j) * D + col]);
    uint4 o;
    o.x = v[0] | (v[1] << 16);
    o.y = v[2] | (v[3] << 16);
    o.z = v[4] | (v[5] << 16);
    o.w = v[6] | (v[7] << 16);
    pack[e] = o;
}

// ================= MFMA GEMM: out = act(X @ W [+ b]) =================
template <bool IN_BF16, bool RELU, bool OUT_BF16, bool BIAS>
__global__ __launch_bounds__(256) void gemm_mfma(
    const void* __restrict__ xin, const uint4* __restrict__ wpack,
    const float* __restrict__ b, void* __restrict__ xout, int n_rows)
{
    __shared__ uint4 xs4[2048];
    __shared__ uint4 ws4[2048];
    const int t = threadIdx.x;
    const int row0 = blockIdx.x * 128;

#pragma unroll
    for (int i = 0; i < 8; ++i) ws4[t + 256 * i] = wpack[t + 256 * i];

    if (IN_BF16) {
        const uint4* g = (const uint4*)xin;
#pragma unroll
        for (int i = 0; i < 8; ++i) {
            int c = t + 256 * i;
            int row = c >> 4, kc = c & 15;
            int grow = row0 + row;
            if (grow < n_rows)
                xs4[row * 16 + (kc ^ (row & 7))] = g[(size_t)grow * 16 + kc];
        }
    } else {
        const float4* g = (const float4*)xin;
#pragma unroll
        for (int i = 0; i < 8; ++i) {
            int c = t + 256 * i;
            int row = c >> 4, kc = c & 15;
            int grow = row0 + row;
            if (grow < n_rows) {
                float4 f0 = g[(size_t)grow * 32 + kc * 2];
                float4 f1 = g[(size_t)grow * 32 + kc * 2 + 1];
                uint4 v;
                v.x = pack2(f0.x, f0.y);
                v.y = pack2(f0.z, f0.w);
                v.z = pack2(f1.x, f1.y);
                v.w = pack2(f1.z, f1.w);
                xs4[row * 16 + (kc ^ (row & 7))] = v;
            }
        }
    }
    __syncthreads();

    const int l = t & 63;
    const int w = t >> 6;
    const int l15 = l & 15;
    const int lk = l >> 4;

    float bias_v[8];
#pragma unroll
    for (int nt = 0; nt < 8; ++nt) bias_v[nt] = BIAS ? b[nt * 16 + l15] : 0.f;

    f32x4 acc[2][8];
#pragma unroll
    for (int rt = 0; rt < 2; ++rt)
#pragma unroll
        for (int nt = 0; nt < 8; ++nt) acc[rt][nt] = (f32x4){0.f, 0.f, 0.f, 0.f};

    const int arow0 = w * 32 + l15;
    const int arow1 = arow0 + 16;

#pragma unroll
    for (int kt = 0; kt < 4; ++kt) {
        int kc0 = kt * 4 + lk;
        short8x a0 = *(const short8x*)&xs4[arow0 * 16 + (kc0 ^ (arow0 & 7))];
        short8x a1 = *(const short8x*)&xs4[arow1 * 16 + (kc0 ^ (arow1 & 7))];
#pragma unroll
        for (int nt = 0; nt < 8; ++nt) {
            short8x bf = *(const short8x*)&ws4[(kt * 8 + nt) * 64 + l];
            acc[0][nt] = __builtin_amdgcn_mfma_f32_16x16x32_bf16(a0, bf, acc[0][nt], 0, 0, 0);
            acc[1][nt] = __builtin_amdgcn_mfma_f32_16x16x32_bf16(a1, bf, acc[1][nt], 0, 0, 0);
        }
    }

    // D layout: col = l&15, row = (l>>4)*4 + reg   [m89-verified]
#pragma unroll
    for (int rt = 0; rt < 2; ++rt) {
#pragma unroll
        for (int r = 0; r < 4; ++r) {
            int row = row0 + w * 32 + rt * 16 + lk * 4 + r;
            if (row >= n_rows) continue;
#pragma unroll
            for (int nt = 0; nt < 8; ++nt) {
                float v = acc[rt][nt][r] + bias_v[nt];
                if (RELU) v = fmaxf(v, 0.f);
                int col = nt * 16 + l15;
                if (OUT_BF16)
                    ((unsigned short*)xout)[(size_t)row * D + col] = (unsigned short)f2bf(v);
                else
                    ((float*)xout)[(size_t)row * D + col] = v;
            }
        }
    }
}

// ================= bucket histogram (LDS-local, few global atomics) =========
__global__ __launch_bounds__(256) void hist_b(
    const int* __restrict__ edst, int* __restrict__ bcnt, int E, int NB)
{
    __shared__ int lcnt[NBMAX];
    const int t = threadIdx.x;
    for (int b = t; b < NB; b += 256) lcnt[b] = 0;
    __syncthreads();
    int cb = blockIdx.x * CHUNK;
    int ce = min(E, cb + CHUNK);
    for (int i = cb + t; i < ce; i += 256)
        atomicAdd(&lcnt[edst[i] >> 8], 1);
    __syncthreads();
    for (int b = t; b < NB; b += 256)
        if (lcnt[b]) atomicAdd(&bcnt[b], lcnt[b]);
}

// ================= exclusive scan over NB buckets (single block) ============
__global__ __launch_bounds__(NBMAX) void scan_b(
    const int* __restrict__ bcnt, int* __restrict__ base, int NB)
{
    __shared__ int sc[NBMAX];
    const int t = threadIdx.x;
    int my = (t < NB) ? bcnt[t] : 0;
    sc[t] = my;
    __syncthreads();
    for (int s = 1; s < NBMAX; s <<= 1) {
        int add = (t >= s) ? sc[t - s] : 0;
        __syncthreads();
        sc[t] += add;
        __syncthreads();
    }
    if (t < NB) base[t] = sc[t] - my;      // exclusive
    if (t == NB) base[NB] = sc[NB - 1 >= 0 ? NB - 1 : 0];  // total (= E)
}

// ================= bucket scatter: segment-contiguous writes ================
// pairs[i] = (src<<8) | (dst & 255), grouped by bucket.
__global__ __launch_bounds__(256) void bucket_scatter(
    const int* __restrict__ esrc, const int* __restrict__ edst,
    const int* __restrict__ base, int* __restrict__ bfill,
    unsigned* __restrict__ pairs, int E, int NB)
{
    __shared__ int lcnt[NBMAX];
    __shared__ int lbase[NBMAX];
    const int t = threadIdx.x;
    for (int b = t; b < NB; b += 256) lcnt[b] = 0;
    __syncthreads();
    int cb = blockIdx.x * CHUNK;
    int ce = min(E, cb + CHUNK);
    for (int i = cb + t; i < ce; i += 256)
        atomicAdd(&lcnt[edst[i] >> 8], 1);
    __syncthreads();
    for (int b = t; b < NB; b += 256) {
        int c = lcnt[b];
        lbase[b] = c ? (base[b] + atomicAdd(&bfill[b], c)) : 0;
        lcnt[b] = 0;    // reuse as local fill
    }
    __syncthreads();
    for (int i = cb + t; i < ce; i += 256) {
        int d = edst[i];
        int s = esrc[i];
        int b = d >> 8;
        int pos = atomicAdd(&lcnt[b], 1);
        pairs[lbase[b] + pos] = ((unsigned)s << 8) | (unsigned)(d & 255);
    }
}

// ================= bucket pull: LDS counting-sort + gather-sum ==============
// One block per 256-node bucket. All sort traffic in LDS; global traffic =
// coalesced pairs reads (2x) + z-row gathers + single out write per row.
__global__ __launch_bounds__(256) void bucket_pull(
    const unsigned* __restrict__ pairs, const int* __restrict__ base,
    const uint2* __restrict__ z2, const float* __restrict__ b2,
    float* __restrict__ out, int* __restrict__ ovfb_cnt,
    int* __restrict__ ovfb_list, int n_nodes)
{
    __shared__ int srcl[BCAP];
    __shared__ int off[NPB + 1];
    __shared__ int fill[NPB];
    __shared__ int scanb[NPB];

    const int bkt = blockIdx.x;
    const int t = threadIdx.x;
    const int nbase = bkt << 8;
    const int ebase = base[bkt];
    const int ecnt = base[bkt + 1] - ebase;
    const int elim = min(ecnt, BCAP);

    if (ecnt > BCAP && t == 0) {
        int o = atomicAdd(ovfb_cnt, 1);
        ovfb_list[o] = bkt;
    }

    fill[t] = 0;
    __syncthreads();
    for (int i = t; i < elim; i += 256)
        atomicAdd(&fill[pairs[ebase + i] & 255], 1);
    __syncthreads();

    int c = fill[t];
    scanb[t] = c;
    __syncthreads();
    for (int s = 1; s < NPB; s <<= 1) {
        int add = (t >= s) ? scanb[t - s] : 0;
        __syncthreads();
        scanb[t] += add;
        __syncthreads();
    }
    off[t] = scanb[t] - c;
    fill[t] = scanb[t] - c;
    if (t == NPB - 1) off[NPB] = scanb[NPB - 1];
    __syncthreads();

    for (int i = t; i < elim; i += 256) {
        unsigned v = pairs[ebase + i];
        int pos = atomicAdd(&fill[v & 255], 1);
        srcl[pos] = (int)(v >> 8);
    }
    __syncthreads();

    const int grp = t >> 5;
    const int lane = t & 31;
    float4 bv = ((const float4*)b2)[lane];

    for (int ln = grp; ln < NPB; ln += 8) {
        int node = nbase + ln;
        if (node >= n_nodes) break;
        int i = off[ln], s1 = off[ln + 1];
        float a0 = 0.f, a1 = 0.f, a2 = 0.f, a3 = 0.f;
        for (; i + 4 <= s1; i += 4) {
            int sa = srcl[i], sb = srcl[i + 1], sc = srcl[i + 2], sd = srcl[i + 3];
            uint2 v0 = z2[(size_t)sa * 32 + lane];
            uint2 v1 = z2[(size_t)sb * 32 + lane];
            uint2 v2 = z2[(size_t)sc * 32 + lane];
            uint2 v3 = z2[(size_t)sd * 32 + lane];
            a0 += bflo(v0.x) + bflo(v1.x) + bflo(v2.x) + bflo(v3.x);
            a1 += bfhi(v0.x) + bfhi(v1.x) + bfhi(v2.x) + bfhi(v3.x);
            a2 += bflo(v0.y) + bflo(v1.y) + bflo(v2.y) + bflo(v3.y);
            a3 += bfhi(v0.y) + bfhi(v1.y) + bfhi(v2.y) + bfhi(v3.y);
        }
        for (; i < s1; ++i) {
            int s = srcl[i];
            uint2 v = z2[(size_t)s * 32 + lane];
            a0 += bflo(v.x); a1 += bfhi(v.x);
            a2 += bflo(v.y); a3 += bfhi(v.y);
        }
        ((float4*)out)[(size_t)node * 32 + lane] =
            make_float4(a0 + bv.x, a1 + bv.y, a2 + bv.z, a3 + bv.w);
    }
}

// Overflow buckets (normally none): add tail edges with f32 atomics.
__global__ __launch_bounds__(32) void ovf_b(
    const int* __restrict__ ovfb_cnt, const int* __restrict__ ovfb_list,
    const int* __restrict__ base, const unsigned* __restrict__ pairs,
    const uint2* __restrict__ z2, float* __restrict__ out)
{
    int n = *ovfb_cnt;
    int lane = threadIdx.x;
    for (int k = blockIdx.x; k < n; k += gridDim.x) {
        int b = ovfb_list[k];
        int ebase = base[b], ecnt = base[b + 1] - base[b];
        for (int i = BCAP; i < ecnt; ++i) {
            unsigned v = pairs[ebase + i];
            int node = (b << 8) + (int)(v & 255);
            int s = (int)(v >> 8);
            uint2 hv = z2[(size_t)s * 32 + lane];
            unsafeAtomicAdd(&out[(size_t)node * D + lane * 4 + 0], bflo(hv.x));
            unsafeAtomicAdd(&out[(size_t)node * D + lane * 4 + 1], bfhi(hv.x));
            unsafeAtomicAdd(&out[(size_t)node * D + lane * 4 + 2], bflo(hv.y));
            unsafeAtomicAdd(&out[(size_t)node * D + lane * 4 + 3], bfhi(hv.y));
        }
    }
}

// ================= fallback path (f32 atomic scatter) =================
template <bool RELU>
__global__ __launch_bounds__(256) void gemm_bias_act(
    const float* xin, const float* __restrict__ W,
    const float* __restrict__ b, float* xout, int n_rows)
{
    __shared__ float Ws[D * D];
    __shared__ float xs[32 * D];
    const int t = threadIdx.x;
    const int row0 = blockIdx.x * 32;
    const float4* Wv = (const float4*)W;
    float4* Wsv = (float4*)Ws;
#pragma unroll
    for (int i = 0; i < 16; ++i) Wsv[t + 256 * i] = Wv[t + 256 * i];
    const float4* xv = (const float4*)xin;
    float4* xsv = (float4*)xs;
#pragma unroll
    for (int i = 0; i < 4; ++i) {
        int f4 = t + 256 * i;
        int row = row0 + (f4 >> 5);
        if (row < n_rows) xsv[f4] = xv[(size_t)row0 * 32 + f4];
    }
    __syncthreads();
    const int cg = t & 31;
    const int rg = t >> 5;
    float4 bias = ((const float4*)b)[cg];
    float4 acc[4];
#pragma unroll
    for (int ri = 0; ri < 4; ++ri) acc[ri] = make_float4(0.f, 0.f, 0.f, 0.f);
#pragma unroll 4
    for (int k = 0; k < D; k += 4) {
        float4 w0 = Wsv[(k + 0) * 32 + cg];
        float4 w1 = Wsv[(k + 1) * 32 + cg];
        float4 w2 = Wsv[(k + 2) * 32 + cg];
        float4 w3 = Wsv[(k + 3) * 32 + cg];
#pragma unroll
        for (int ri = 0; ri < 4; ++ri) {
            float4 xa = xsv[(rg + 8 * ri) * 32 + (k >> 2)];
            acc[ri].x = fmaf(xa.x, w0.x, fmaf(xa.y, w1.x, fmaf(xa.z, w2.x, fmaf(xa.w, w3.x, acc[ri].x))));
            acc[ri].y = fmaf(xa.x, w0.y, fmaf(xa.y, w1.y, fmaf(xa.z, w2.y, fmaf(xa.w, w3.y, acc[ri].y))));
            acc[ri].z = fmaf(xa.x, w0.z, fmaf(xa.y, w1.z, fmaf(xa.z, w2.z, fmaf(xa.w, w3.z, acc[ri].z))));
            acc[ri].w = fmaf(xa.x, w0.w, fmaf(xa.y, w1.w, fmaf(xa.z, w2.w, fmaf(xa.w, w3.w, acc[ri].w))));
        }
    }
#pragma unroll
    for (int ri = 0; ri < 4; ++ri) {
        int row = row0 + rg + 8 * ri;
        if (row >= n_rows) continue;
        float4 o;
        o.x = acc[ri].x + bias.x; o.y = acc[ri].y + bias.y;
        o.z = acc[ri].z + bias.z; o.w = acc[ri].w + bias.w;
        if (RELU) {
            o.x = fmaxf(o.x, 0.f); o.y = fmaxf(o.y, 0.f);
            o.z = fmaxf(o.z, 0.f); o.w = fmaxf(o.w, 0.f);
        }
        ((float4*)xout)[(size_t)row * 32 + cg] = o;
    }
}

__global__ __launch_bounds__(256) void zero_kernel(float4* p, int n4)
{
    int i = blockIdx.x * 256 + threadIdx.x;
    int stride = gridDim.x * 256;
    for (; i < n4; i += stride) p[i] = make_float4(0.f, 0.f, 0.f, 0.f);
}

__global__ __launch_bounds__(256) void scatter_kernel(
    const float* __restrict__ h, const int* __restrict__ esrc,
    const int* __restrict__ edst, float* __restrict__ agg, long n_items)
{
    long idx = (long)blockIdx.x * 256 + threadIdx.x;
    long stride = (long)gridDim.x * 256;
    for (; idx < n_items; idx += stride) {
        int e = (int)(idx >> 7);
        int c = (int)(idx & 127);
        int s = esrc[e];
        int d = edst[e];
        unsafeAtomicAdd(&agg[(size_t)d * D + c], h[(size_t)s * D + c]);
    }
}

extern "C" void kernel_launch(void* const* d_in, const int* in_sizes, int n_in,
                              void* d_out, int out_size, void* d_ws, size_t ws_size,
                              hipStream_t stream)
{
    const float* x    = (const float*)d_in[0];
    const int*   esrc = (const int*)d_in[1];
    const int*   edst = (const int*)d_in[2];
    const float* W1   = (const float*)d_in[3];
    const float* b1   = (const float*)d_in[4];
    const float* W2   = (const float*)d_in[5];
    const float* b2   = (const float*)d_in[6];
    float* out = (float*)d_out;

    const int N = in_sizes[0] / D;   // 100000
    const int E = in_sizes[1];       // 1600000
    const int NB = (N + NPB - 1) / NPB;   // 391

    char* ws = (char*)d_ws;
    size_t off_h     = 0;
    size_t off_z     = off_h + (size_t)N * 256;           // h2: 25.6 MB
    size_t off_pairs = off_z + (size_t)N * 256;           // z2: 25.6 MB
    size_t off_base  = (off_pairs + (size_t)E * 4 + 255) & ~(size_t)255;
    size_t off_zero  = off_base + (NBMAX + 1) * 4;        // bcnt | bfill | ovfb_cnt
    size_t off_bcnt  = off_zero;
    size_t off_bfill = off_bcnt + NBMAX * 4;
    size_t off_ovfc  = off_bfill + NBMAX * 4;
    size_t off_ovfl  = off_ovfc + 64;
    size_t off_pack  = (off_ovfl + NBMAX * 4 + 255) & ~(size_t)255;
    size_t need      = off_pack + 65536;

    const int nblk = (N + 127) / 128;          // 782
    const int gchunk = (E + CHUNK - 1) / CHUNK; // 196

    if (ws_size >= need && N <= NBMAX * NPB) {
        uint2*    h2    = (uint2*)(ws + off_h);
        uint2*    z2    = (uint2*)(ws + off_z);
        unsigned* pairs = (unsigned*)(ws + off_pairs);
        int*      base  = (int*)(ws + off_base);
        int*      bcnt  = (int*)(ws + off_bcnt);
        int*      bfill = (int*)(ws + off_bfill);
        int*      ovfc  = (int*)(ws + off_ovfc);
        int*      ovfl  = (int*)(ws + off_ovfl);
        uint4*    pack  = (uint4*)(ws + off_pack);

        hipMemsetAsync(ws + off_zero, 0, off_ovfl + NBMAX * 4 - off_zero, stream);

        // 0) pack weights
        pack_w<<<16, 256, 0, stream>>>(W1, W2, pack);

        // 1) CSR-by-bucket build (all writes coalesced / segment-contiguous)
        hist_b<<<gchunk, 256, 0, stream>>>(edst, bcnt, E, NB);
        scan_b<<<1, NBMAX, 0, stream>>>(bcnt, base, NB);
        bucket_scatter<<<gchunk, 256, 0, stream>>>(esrc, edst, base, bfill, pairs, E, NB);

        // 2) h = relu(x @ W1 + b1), bf16
        gemm_mfma<false, true, true, true><<<nblk, 256, 0, stream>>>(x, pack, b1, h2, N);

        // 3) z = h @ W2 (no bias), bf16   [agg@W2+b2 == segsum(h@W2)+b2]
        gemm_mfma<true, false, true, false><<<nblk, 256, 0, stream>>>(h2, pack + 2048, nullptr, z2, N);

        // 4) per-bucket LDS counting-sort + gather-sum, out = segsum + b2
        bucket_pull<<<NB, 256, 0, stream>>>(pairs, base, z2, b2, out, ovfc, ovfl, N);

        // 5) overflow buckets (normally zero)
        ovf_b<<<16, 32, 0, stream>>>(ovfc, ovfl, base, pairs, z2, out);
    } else {
        float* h = (float*)ws;
        const int nb32 = (N + 31) / 32;
        gemm_bias_act<true><<<nb32, 256, 0, stream>>>(x, W1, b1, h, N);
        zero_kernel<<<2048, 256, 0, stream>>>((float4*)out, N * D / 4);
        scatter_kernel<<<8192, 256, 0, stream>>>(h, esrc, edst, out, (long)E * D);
        gemm_bias_act<false><<<nb32, 256, 0, stream>>>(out, W2, b2, out, N);
    }
}

// Round 8
// 139.257 us; speedup vs baseline: 1.8569x; 1.4012x over previous
//
#include <hip/hip_runtime.h>

#define D 128
#define NPB 256            // nodes per bucket (dst>>8)
#define NBMAX 512          // max buckets (N <= 131072)
#define BKCAP 8192         // edge capacity per bucket (mean 4096, +64 sigma)
#define CHUNK 8192         // edges per workgroup in scatter
#define OVF_CAP 8192

typedef __attribute__((ext_vector_type(8))) short short8x;
typedef __attribute__((ext_vector_type(4))) float f32x4;

// ---- bf16 helpers (manual RNE) ----
__device__ inline unsigned int f2bf(float f) {
    unsigned int u = __builtin_bit_cast(unsigned int, f);
    return (u + 0x7fffu + ((u >> 16) & 1u)) >> 16;
}
__device__ inline float bflo(unsigned int v) {
    return __builtin_bit_cast(float, v << 16);
}
__device__ inline float bfhi(unsigned int v) {
    return __builtin_bit_cast(float, v & 0xffff0000u);
}
__device__ inline unsigned int pack2(float lo, float hi) {
    return f2bf(lo) | (f2bf(hi) << 16);
}

// ================= W pre-pack: lane-linear bf16 B fragments =================
__global__ __launch_bounds__(256) void pack_w(
    const float* __restrict__ W1, const float* __restrict__ W2,
    uint4* __restrict__ pack)
{
    int e = blockIdx.x * 256 + threadIdx.x;      // 0..4095
    const float* W = (e & 2048) ? W2 : W1;
    int f = (e >> 6) & 31, l = e & 63;
    int kt = f >> 3, nt = f & 7;
    int k0 = kt * 32 + (l >> 4) * 8;
    int col = nt * 16 + (l & 15);
    unsigned int v[8];
#pragma unroll
    for (int j = 0; j < 8; ++j) v[j] = f2bf(W[(size_t)(k0 + j) * D + col]);
    uint4 o;
    o.x = v[0] | (v[1] << 16);
    o.y = v[2] | (v[3] << 16);
    o.z = v[4] | (v[5] << 16);
    o.w = v[6] | (v[7] << 16);
    pack[e] = o;
}

// ========== fused GEMM: z = (relu(x@W1+b1)) @ W2, h only in LDS ==========
// 256 thr = 4 waves, 64 rows/block. LDS: W1 32KB + W2 32KB + x/h tile 16KB
// = 80KB -> 2 blocks/CU. h tile overwrites the x tile after a barrier.
__global__ __launch_bounds__(256) void gemm_fused(
    const float* __restrict__ xin, const uint4* __restrict__ wpack,
    const float* __restrict__ b1, unsigned short* __restrict__ zout, int n_rows)
{
    __shared__ uint4 ws1[2048];
    __shared__ uint4 ws2[2048];
    __shared__ uint4 xs4[1024];   // 64 rows x 16 uint4 (128 bf16), swizzled

    const int t = threadIdx.x;
    const int row0 = blockIdx.x * 64;

#pragma unroll
    for (int i = 0; i < 8; ++i) ws1[t + 256 * i] = wpack[t + 256 * i];
#pragma unroll
    for (int i = 0; i < 8; ++i) ws2[t + 256 * i] = wpack[2048 + t + 256 * i];

    const float4* g = (const float4*)xin;
#pragma unroll
    for (int i = 0; i < 4; ++i) {
        int c = t + 256 * i;              // 0..1023
        int row = c >> 4, kc = c & 15;
        int grow = row0 + row;
        if (grow < n_rows) {
            float4 f0 = g[(size_t)grow * 32 + kc * 2];
            float4 f1 = g[(size_t)grow * 32 + kc * 2 + 1];
            uint4 v;
            v.x = pack2(f0.x, f0.y);
            v.y = pack2(f0.z, f0.w);
            v.z = pack2(f1.x, f1.y);
            v.w = pack2(f1.z, f1.w);
            xs4[row * 16 + (kc ^ (row & 7))] = v;
        }
    }
    __syncthreads();

    const int l = t & 63;
    const int w = t >> 6;
    const int l15 = l & 15;
    const int lk = l >> 4;
    const int arow = w * 16 + l15;        // this wave's A row for both GEMMs

    float bias1[8];
#pragma unroll
    for (int nt = 0; nt < 8; ++nt) bias1[nt] = b1[nt * 16 + l15];

    f32x4 acc1[8];
#pragma unroll
    for (int nt = 0; nt < 8; ++nt) acc1[nt] = (f32x4){0.f, 0.f, 0.f, 0.f};

#pragma unroll
    for (int kt = 0; kt < 4; ++kt) {
        short8x a = *(const short8x*)&xs4[arow * 16 + ((kt * 4 + lk) ^ (arow & 7))];
#pragma unroll
        for (int nt = 0; nt < 8; ++nt) {
            short8x bf = *(const short8x*)&ws1[(kt * 8 + nt) * 64 + l];
            acc1[nt] = __builtin_amdgcn_mfma_f32_16x16x32_bf16(a, bf, acc1[nt], 0, 0, 0);
        }
    }
    __syncthreads();   // all xs reads done -> safe to overwrite with h

    // h = relu(acc1 + b1) into xs4 (bf16, same swizzle). D layout: col=l&15,
    // row=(l>>4)*4+r  [m89-verified]
    unsigned short* hsu = (unsigned short*)xs4;
#pragma unroll
    for (int nt = 0; nt < 8; ++nt) {
        int col = nt * 16 + l15;
        int ci = (col >> 3), ce = (col & 7);
#pragma unroll
        for (int r = 0; r < 4; ++r) {
            int rowl = w * 16 + lk * 4 + r;
            float v = fmaxf(acc1[nt][r] + bias1[nt], 0.f);
            hsu[(rowl * 16 + (ci ^ (rowl & 7))) * 8 + ce] = (unsigned short)f2bf(v);
        }
    }
    __syncthreads();

    f32x4 acc2[8];
#pragma unroll
    for (int nt = 0; nt < 8; ++nt) acc2[nt] = (f32x4){0.f, 0.f, 0.f, 0.f};

#pragma unroll
    for (int kt = 0; kt < 4; ++kt) {
        short8x a = *(const short8x*)&xs4[arow * 16 + ((kt * 4 + lk) ^ (arow & 7))];
#pragma unroll
        for (int nt = 0; nt < 8; ++nt) {
            short8x bf = *(const short8x*)&ws2[(kt * 8 + nt) * 64 + l];
            acc2[nt] = __builtin_amdgcn_mfma_f32_16x16x32_bf16(a, bf, acc2[nt], 0, 0, 0);
        }
    }

    // z (no bias; b2 added in pull), bf16
#pragma unroll
    for (int r = 0; r < 4; ++r) {
        int row = row0 + w * 16 + lk * 4 + r;
        if (row >= n_rows) continue;
#pragma unroll
        for (int nt = 0; nt < 8; ++nt) {
            int col = nt * 16 + l15;
            zout[(size_t)row * D + col] = (unsigned short)f2bf(acc2[nt][r]);
        }
    }
}

// ========== bucket scatter: fixed-capacity segments, coalesced writes =======
// pairs[b*BKCAP + i] = (src<<8) | (dst&255). One global atomicAdd per
// (chunk,bucket); per-edge writes confined to the bucket's private segment.
__global__ __launch_bounds__(256) void bucket_scatter(
    const int* __restrict__ esrc, const int* __restrict__ edst,
    int* __restrict__ gfill, unsigned* __restrict__ pairs,
    int* __restrict__ ovf_cnt, int2* __restrict__ ovf_list, int E, int NB)
{
    __shared__ int lcnt[NBMAX];
    __shared__ int lbase[NBMAX];
    const int t = threadIdx.x;
    for (int b = t; b < NB; b += 256) lcnt[b] = 0;
    __syncthreads();
    int cb = blockIdx.x * CHUNK;
    int ce = min(E, cb + CHUNK);
    for (int i = cb + t; i < ce; i += 256)
        atomicAdd(&lcnt[edst[i] >> 8], 1);
    __syncthreads();
    for (int b = t; b < NB; b += 256) {
        int c = lcnt[b];
        lbase[b] = c ? atomicAdd(&gfill[b], c) : 0;
        lcnt[b] = 0;
    }
    __syncthreads();
    for (int i = cb + t; i < ce; i += 256) {
        int d = edst[i];
        int s = esrc[i];
        int b = d >> 8;
        int pos = lbase[b] + atomicAdd(&lcnt[b], 1);
        if (pos < BKCAP) {
            pairs[(size_t)b * BKCAP + pos] = ((unsigned)s << 8) | (unsigned)(d & 255);
        } else {
            int o = atomicAdd(ovf_cnt, 1);
            if (o < OVF_CAP) ovf_list[o] = make_int2(s, d);
        }
    }
}

// ========== node sort: bucket pairs -> global CSR (srcs + (start,count)) ====
// One block per bucket, ~3KB LDS. Global writes confined to the bucket's
// private srcs segment (L2-merged).
__global__ __launch_bounds__(256) void node_sort(
    const unsigned* __restrict__ pairs, const int* __restrict__ gfill,
    int* __restrict__ srcs, int2* __restrict__ noff2, int n_nodes)
{
    __shared__ int fill[NPB];
    __shared__ int scanb[NPB];
    const int bkt = blockIdx.x;
    const int t = threadIdx.x;
    const size_t ebase = (size_t)bkt * BKCAP;
    const int ecnt = min(gfill[bkt], BKCAP);

    fill[t] = 0;
    __syncthreads();
    for (int i = t; i < ecnt; i += 256)
        atomicAdd(&fill[pairs[ebase + i] & 255], 1);
    __syncthreads();

    int c = fill[t];
    scanb[t] = c;
    __syncthreads();
    for (int s = 1; s < NPB; s <<= 1) {
        int add = (t >= s) ? scanb[t - s] : 0;
        __syncthreads();
        scanb[t] += add;
        __syncthreads();
    }
    int off = scanb[t] - c;               // exclusive
    int node = (bkt << 8) + t;
    if (node < n_nodes) noff2[node] = make_int2((int)ebase + off, c);
    fill[t] = off;
    __syncthreads();

    for (int i = t; i < ecnt; i += 256) {
        unsigned v = pairs[ebase + i];
        int pos = atomicAdd(&fill[v & 255], 1);
        srcs[ebase + pos] = (int)(v >> 8);
    }
}

// ========== pull: out[n] = sum_{csr} z[src] + b2 (f32) ======================
// 32 lanes/node, 8 nodes/block, no LDS -> max occupancy; 4 rows in flight.
__global__ __launch_bounds__(256) void pull_csr(
    const uint2* __restrict__ z2, const int* __restrict__ srcs,
    const int2* __restrict__ noff2, const float* __restrict__ b2,
    float* __restrict__ out, int n_nodes)
{
    int node = blockIdx.x * 8 + (threadIdx.x >> 5);
    int lane = threadIdx.x & 31;
    if (node >= n_nodes) return;
    int2 se = noff2[node];
    int i = se.x, end = se.x + se.y;

    float a0 = 0.f, a1 = 0.f, a2 = 0.f, a3 = 0.f;
    for (; i + 4 <= end; i += 4) {
        int sa = srcs[i], sb = srcs[i + 1], sc = srcs[i + 2], sd = srcs[i + 3];
        uint2 v0 = z2[(size_t)sa * 32 + lane];
        uint2 v1 = z2[(size_t)sb * 32 + lane];
        uint2 v2 = z2[(size_t)sc * 32 + lane];
        uint2 v3 = z2[(size_t)sd * 32 + lane];
        a0 += bflo(v0.x) + bflo(v1.x) + bflo(v2.x) + bflo(v3.x);
        a1 += bfhi(v0.x) + bfhi(v1.x) + bfhi(v2.x) + bfhi(v3.x);
        a2 += bflo(v0.y) + bflo(v1.y) + bflo(v2.y) + bflo(v3.y);
        a3 += bfhi(v0.y) + bfhi(v1.y) + bfhi(v2.y) + bfhi(v3.y);
    }
    for (; i < end; ++i) {
        int s = srcs[i];
        uint2 v = z2[(size_t)s * 32 + lane];
        a0 += bflo(v.x); a1 += bfhi(v.x);
        a2 += bflo(v.y); a3 += bfhi(v.y);
    }
    float4 bv = ((const float4*)b2)[lane];
    ((float4*)out)[(size_t)node * 32 + lane] =
        make_float4(a0 + bv.x, a1 + bv.y, a2 + bv.z, a3 + bv.w);
}

// Overflow edges (normally zero): out[d] += z[s], f32 atomics.
__global__ __launch_bounds__(32) void ovf_f32(
    const int* __restrict__ ovf_cnt, const int2* __restrict__ ovf_list,
    const uint2* __restrict__ z2, float* __restrict__ out)
{
    int n = *ovf_cnt;
    if (n > OVF_CAP) n = OVF_CAP;
    int lane = threadIdx.x;
    for (int i = blockIdx.x; i < n; i += gridDim.x) {
        int2 sd = ovf_list[i];
        uint2 v = z2[(size_t)sd.x * 32 + lane];
        unsafeAtomicAdd(&out[(size_t)sd.y * D + lane * 4 + 0], bflo(v.x));
        unsafeAtomicAdd(&out[(size_t)sd.y * D + lane * 4 + 1], bfhi(v.x));
        unsafeAtomicAdd(&out[(size_t)sd.y * D + lane * 4 + 2], bflo(v.y));
        unsafeAtomicAdd(&out[(size_t)sd.y * D + lane * 4 + 3], bfhi(v.y));
    }
}

// ================= fallback path (f32 atomic scatter) =================
template <bool RELU>
__global__ __launch_bounds__(256) void gemm_bias_act(
    const float* xin, const float* __restrict__ W,
    const float* __restrict__ b, float* xout, int n_rows)
{
    __shared__ float Ws[D * D];
    __shared__ float xs[32 * D];
    const int t = threadIdx.x;
    const int row0 = blockIdx.x * 32;
    const float4* Wv = (const float4*)W;
    float4* Wsv = (float4*)Ws;
#pragma unroll
    for (int i = 0; i < 16; ++i) Wsv[t + 256 * i] = Wv[t + 256 * i];
    const float4* xv = (const float4*)xin;
    float4* xsv = (float4*)xs;
#pragma unroll
    for (int i = 0; i < 4; ++i) {
        int f4 = t + 256 * i;
        int row = row0 + (f4 >> 5);
        if (row < n_rows) xsv[f4] = xv[(size_t)row0 * 32 + f4];
    }
    __syncthreads();
    const int cg = t & 31;
    const int rg = t >> 5;
    float4 bias = ((const float4*)b)[cg];
    float4 acc[4];
#pragma unroll
    for (int ri = 0; ri < 4; ++ri) acc[ri] = make_float4(0.f, 0.f, 0.f, 0.f);
#pragma unroll 4
    for (int k = 0; k < D; k += 4) {
        float4 w0 = Wsv[(k + 0) * 32 + cg];
        float4 w1 = Wsv[(k + 1) * 32 + cg];
        float4 w2 = Wsv[(k + 2) * 32 + cg];
        float4 w3 = Wsv[(k + 3) * 32 + cg];
#pragma unroll
        for (int ri = 0; ri < 4; ++ri) {
            float4 xa = xsv[(rg + 8 * ri) * 32 + (k >> 2)];
            acc[ri].x = fmaf(xa.x, w0.x, fmaf(xa.y, w1.x, fmaf(xa.z, w2.x, fmaf(xa.w, w3.x, acc[ri].x))));
            acc[ri].y = fmaf(xa.x, w0.y, fmaf(xa.y, w1.y, fmaf(xa.z, w2.y, fmaf(xa.w, w3.y, acc[ri].y))));
            acc[ri].z = fmaf(xa.x, w0.z, fmaf(xa.y, w1.z, fmaf(xa.z, w2.z, fmaf(xa.w, w3.z, acc[ri].z))));
            acc[ri].w = fmaf(xa.x, w0.w, fmaf(xa.y, w1.w, fmaf(xa.z, w2.w, fmaf(xa.w, w3.w, acc[ri].w))));
        }
    }
#pragma unroll
    for (int ri = 0; ri < 4; ++ri) {
        int row = row0 + rg + 8 * ri;
        if (row >= n_rows) continue;
        float4 o;
        o.x = acc[ri].x + bias.x; o.y = acc[ri].y + bias.y;
        o.z = acc[ri].z + bias.z; o.w = acc[ri].w + bias.w;
        if (RELU) {
            o.x = fmaxf(o.x, 0.f); o.y = fmaxf(o.y, 0.f);
            o.z = fmaxf(o.z, 0.f); o.w = fmaxf(o.w, 0.f);
        }
        ((float4*)xout)[(size_t)row * 32 + cg] = o;
    }
}

__global__ __launch_bounds__(256) void zero_kernel(float4* p, int n4)
{
    int i = blockIdx.x * 256 + threadIdx.x;
    int stride = gridDim.x * 256;
    for (; i < n4; i += stride) p[i] = make_float4(0.f, 0.f, 0.f, 0.f);
}

__global__ __launch_bounds__(256) void scatter_kernel(
    const float* __restrict__ h, const int* __restrict__ esrc,
    const int* __restrict__ edst, float* __restrict__ agg, long n_items)
{
    long idx = (long)blockIdx.x * 256 + threadIdx.x;
    long stride = (long)gridDim.x * 256;
    for (; idx < n_items; idx += stride) {
        int e = (int)(idx >> 7);
        int c = (int)(idx & 127);
        int s = esrc[e];
        int d = edst[e];
        unsafeAtomicAdd(&agg[(size_t)d * D + c], h[(size_t)s * D + c]);
    }
}

extern "C" void kernel_launch(void* const* d_in, const int* in_sizes, int n_in,
                              void* d_out, int out_size, void* d_ws, size_t ws_size,
                              hipStream_t stream)
{
    const float* x    = (const float*)d_in[0];
    const int*   esrc = (const int*)d_in[1];
    const int*   edst = (const int*)d_in[2];
    const float* W1   = (const float*)d_in[3];
    const float* b1   = (const float*)d_in[4];
    const float* W2   = (const float*)d_in[5];
    const float* b2   = (const float*)d_in[6];
    float* out = (float*)d_out;

    const int N = in_sizes[0] / D;   // 100000
    const int E = in_sizes[1];       // 1600000
    const int NB = (N + NPB - 1) / NPB;   // 391

    char* ws = (char*)d_ws;
    size_t off_z     = 0;                                        // z2: 25.6 MB
    size_t off_pairs = off_z + (size_t)N * 256;
    size_t off_srcs  = off_pairs + (size_t)NBMAX * BKCAP * 4;    // 16.8 MB
    size_t off_noff  = off_srcs + (size_t)NBMAX * BKCAP * 4;     // 16.8 MB
    size_t off_gfill = (off_noff + (size_t)N * 8 + 255) & ~(size_t)255;
    size_t off_ovfc  = off_gfill + NBMAX * 4;
    size_t off_ovfl  = off_ovfc + 16;
    size_t off_pack  = (off_ovfl + (size_t)OVF_CAP * 8 + 255) & ~(size_t)255;
    size_t need      = off_pack + 65536;

    const int gchunk = (E + CHUNK - 1) / CHUNK;   // 196

    if (ws_size >= need && N <= NBMAX * NPB) {
        uint2*    z2    = (uint2*)(ws + off_z);
        unsigned* pairs = (unsigned*)(ws + off_pairs);
        int*      srcs  = (int*)(ws + off_srcs);
        int2*     noff2 = (int2*)(ws + off_noff);
        int*      gfill = (int*)(ws + off_gfill);
        int*      ovfc  = (int*)(ws + off_ovfc);
        int2*     ovfl  = (int2*)(ws + off_ovfl);
        uint4*    pack  = (uint4*)(ws + off_pack);

        hipMemsetAsync(gfill, 0, NBMAX * 4 + 16, stream);   // gfill + ovfc

        // 0) pack weights
        pack_w<<<16, 256, 0, stream>>>(W1, W2, pack);

        // 1) bucket the edges (segment-confined writes)
        bucket_scatter<<<gchunk, 256, 0, stream>>>(
            esrc, edst, gfill, pairs, ovfc, ovfl, E, NB);

        // 2) bucket pairs -> global CSR
        node_sort<<<NB, 256, 0, stream>>>(pairs, gfill, srcs, noff2, N);

        // 3) z = relu(x@W1+b1)@W2, bf16 (h stays in LDS)
        gemm_fused<<<(N + 63) / 64, 256, 0, stream>>>(
            x, pack, b1, (unsigned short*)z2, N);

        // 4) out[n] = sum z[src] + b2 (f32, high-occupancy gather)
        pull_csr<<<(N + 7) / 8, 256, 0, stream>>>(z2, srcs, noff2, b2, out, N);

        // 5) overflow edges (normally zero)
        ovf_f32<<<8, 32, 0, stream>>>(ovfc, ovfl, z2, out);
    } else {
        float* h = (float*)ws;
        const int nb32 = (N + 31) / 32;
        gemm_bias_act<true><<<nb32, 256, 0, stream>>>(x, W1, b1, h, N);
        zero_kernel<<<2048, 256, 0, stream>>>((float4*)out, N * D / 4);
        scatter_kernel<<<8192, 256, 0, stream>>>(h, esrc, edst, out, (long)E * D);
        gemm_bias_act<false><<<nb32, 256, 0, stream>>>(out, W2, b2, out, N);
    }
}

// Round 9
// 123.907 us; speedup vs baseline: 2.0869x; 1.1239x over previous
//
#include <hip/hip_runtime.h>

#define D 128
#define NPB 256            // nodes per bucket (dst>>8)
#define NBMAX 512          // max buckets (N <= 131072)
#define BKCAP 8192         // edge capacity per bucket (mean 4096, +64 sigma)
#define CHUNK 8192         // edges per scatter block
#define OVF_CAP 8192

typedef __attribute__((ext_vector_type(8))) short short8x;
typedef __attribute__((ext_vector_type(4))) float f32x4;

// ---- bf16 helpers (manual RNE) ----
__device__ inline unsigned int f2bf(float f) {
    unsigned int u = __builtin_bit_cast(unsigned int, f);
    return (u + 0x7fffu + ((u >> 16) & 1u)) >> 16;
}
__device__ inline float bflo(unsigned int v) {
    return __builtin_bit_cast(float, v << 16);
}
__device__ inline float bfhi(unsigned int v) {
    return __builtin_bit_cast(float, v & 0xffff0000u);
}
__device__ inline unsigned int pack2(float lo, float hi) {
    return f2bf(lo) | (f2bf(hi) << 16);
}

// ================= W pre-pack: lane-linear bf16 B fragments =================
__global__ __launch_bounds__(256) void pack_w(
    const float* __restrict__ W1, const float* __restrict__ W2,
    uint4* __restrict__ pack)
{
    int e = blockIdx.x * 256 + threadIdx.x;      // 0..4095
    const float* W = (e & 2048) ? W2 : W1;
    int f = (e >> 6) & 31, l = e & 63;
    int kt = f >> 3, nt = f & 7;
    int k0 = kt * 32 + (l >> 4) * 8;
    int col = nt * 16 + (l & 15);
    unsigned int v[8];
#pragma unroll
    for (int j = 0; j < 8; ++j) v[j] = f2bf(W[(size_t)(k0 + j) * D + col]);
    uint4 o;
    o.x = v[0] | (v[1] << 16);
    o.y = v[2] | (v[3] << 16);
    o.z = v[4] | (v[5] << 16);
    o.w = v[6] | (v[7] << 16);
    pack[e] = o;
}

// ========== FUSED: bucket_scatter blocks + gemm blocks (independent) ========
// blocks [0, nscatter): edge bucketing (4KB of LDS used)
// blocks [nscatter, ...): z = relu(x@W1+b1)@W2, h in LDS (80KB)
// Overlap: scatter is latency/LDS-atomic-bound, gemm is MFMA/BW-bound.
__global__ __launch_bounds__(256) void build_gemm(
    const int* __restrict__ esrc, const int* __restrict__ edst,
    int* __restrict__ gfill, unsigned* __restrict__ pairs,
    int* __restrict__ ovf_cnt, int2* __restrict__ ovf_list, int E, int NB,
    int nscatter,
    const float* __restrict__ xin, const uint4* __restrict__ wpack,
    const float* __restrict__ b1, unsigned short* __restrict__ zout, int n_rows)
{
    __shared__ __align__(16) char smem[81920];
    const int t = threadIdx.x;

    if (blockIdx.x < nscatter) {
        // ---------------- bucket scatter ----------------
        int* lcnt  = (int*)smem;
        int* lbase = lcnt + NBMAX;
        for (int b = t; b < NB; b += 256) lcnt[b] = 0;
        __syncthreads();
        int cb = blockIdx.x * CHUNK;
        int ce = min(E, cb + CHUNK);
        for (int i = cb + t; i < ce; i += 256)
            atomicAdd(&lcnt[edst[i] >> 8], 1);
        __syncthreads();
        for (int b = t; b < NB; b += 256) {
            int c = lcnt[b];
            lbase[b] = c ? atomicAdd(&gfill[b], c) : 0;
            lcnt[b] = 0;
        }
        __syncthreads();
        for (int i = cb + t; i < ce; i += 256) {
            int d = edst[i];
            int s = esrc[i];
            int b = d >> 8;
            int pos = lbase[b] + atomicAdd(&lcnt[b], 1);
            if (pos < BKCAP) {
                pairs[(size_t)b * BKCAP + pos] = ((unsigned)s << 8) | (unsigned)(d & 255);
            } else {
                int o = atomicAdd(ovf_cnt, 1);
                if (o < OVF_CAP) ovf_list[o] = make_int2(s, d);
            }
        }
        return;
    }

    // ---------------- fused GEMM ----------------
    uint4* ws1 = (uint4*)smem;          // 32KB
    uint4* ws2 = ws1 + 2048;            // 32KB
    uint4* xs4 = ws2 + 2048;            // 16KB (64 rows x 16 uint4, swizzled)
    const int row0 = (blockIdx.x - nscatter) * 64;

#pragma unroll
    for (int i = 0; i < 8; ++i) ws1[t + 256 * i] = wpack[t + 256 * i];
#pragma unroll
    for (int i = 0; i < 8; ++i) ws2[t + 256 * i] = wpack[2048 + t + 256 * i];

    const float4* g = (const float4*)xin;
#pragma unroll
    for (int i = 0; i < 4; ++i) {
        int c = t + 256 * i;              // 0..1023
        int row = c >> 4, kc = c & 15;
        int grow = row0 + row;
        if (grow < n_rows) {
            float4 f0 = g[(size_t)grow * 32 + kc * 2];
            float4 f1 = g[(size_t)grow * 32 + kc * 2 + 1];
            uint4 v;
            v.x = pack2(f0.x, f0.y);
            v.y = pack2(f0.z, f0.w);
            v.z = pack2(f1.x, f1.y);
            v.w = pack2(f1.z, f1.w);
            xs4[row * 16 + (kc ^ (row & 7))] = v;
        }
    }
    __syncthreads();

    const int l = t & 63;
    const int w = t >> 6;
    const int l15 = l & 15;
    const int lk = l >> 4;
    const int arow = w * 16 + l15;

    float bias1[8];
#pragma unroll
    for (int nt = 0; nt < 8; ++nt) bias1[nt] = b1[nt * 16 + l15];

    f32x4 acc1[8];
#pragma unroll
    for (int nt = 0; nt < 8; ++nt) acc1[nt] = (f32x4){0.f, 0.f, 0.f, 0.f};

#pragma unroll
    for (int kt = 0; kt < 4; ++kt) {
        short8x a = *(const short8x*)&xs4[arow * 16 + ((kt * 4 + lk) ^ (arow & 7))];
#pragma unroll
        for (int nt = 0; nt < 8; ++nt) {
            short8x bf = *(const short8x*)&ws1[(kt * 8 + nt) * 64 + l];
            acc1[nt] = __builtin_amdgcn_mfma_f32_16x16x32_bf16(a, bf, acc1[nt], 0, 0, 0);
        }
    }
    __syncthreads();   // xs reads done -> overwrite with h

    // h = relu(acc1 + b1), bf16, same swizzle. D layout: col=l&15, row=lk*4+r
    unsigned short* hsu = (unsigned short*)xs4;
#pragma unroll
    for (int nt = 0; nt < 8; ++nt) {
        int col = nt * 16 + l15;
        int ci = (col >> 3), ce2 = (col & 7);
#pragma unroll
        for (int r = 0; r < 4; ++r) {
            int rowl = w * 16 + lk * 4 + r;
            float v = fmaxf(acc1[nt][r] + bias1[nt], 0.f);
            hsu[(rowl * 16 + (ci ^ (rowl & 7))) * 8 + ce2] = (unsigned short)f2bf(v);
        }
    }
    __syncthreads();

    f32x4 acc2[8];
#pragma unroll
    for (int nt = 0; nt < 8; ++nt) acc2[nt] = (f32x4){0.f, 0.f, 0.f, 0.f};

#pragma unroll
    for (int kt = 0; kt < 4; ++kt) {
        short8x a = *(const short8x*)&xs4[arow * 16 + ((kt * 4 + lk) ^ (arow & 7))];
#pragma unroll
        for (int nt = 0; nt < 8; ++nt) {
            short8x bf = *(const short8x*)&ws2[(kt * 8 + nt) * 64 + l];
            acc2[nt] = __builtin_amdgcn_mfma_f32_16x16x32_bf16(a, bf, acc2[nt], 0, 0, 0);
        }
    }

    // z (no bias; b2 added in pull), bf16
#pragma unroll
    for (int r = 0; r < 4; ++r) {
        int row = row0 + w * 16 + lk * 4 + r;
        if (row >= n_rows) continue;
#pragma unroll
        for (int nt = 0; nt < 8; ++nt) {
            int col = nt * 16 + l15;
            zout[(size_t)row * D + col] = (unsigned short)f2bf(acc2[nt][r]);
        }
    }
}

// ========== node sort: bucket pairs -> global CSR (srcs + (start,count)) ====
__global__ __launch_bounds__(256) void node_sort(
    const unsigned* __restrict__ pairs, const int* __restrict__ gfill,
    int* __restrict__ srcs, int2* __restrict__ noff2, int n_nodes)
{
    __shared__ int fill[NPB];
    __shared__ int scanb[NPB];
    const int bkt = blockIdx.x;
    const int t = threadIdx.x;
    const size_t ebase = (size_t)bkt * BKCAP;
    const int ecnt = min(gfill[bkt], BKCAP);

    fill[t] = 0;
    __syncthreads();
    for (int i = t; i < ecnt; i += 256)
        atomicAdd(&fill[pairs[ebase + i] & 255], 1);
    __syncthreads();

    int c = fill[t];
    scanb[t] = c;
    __syncthreads();
    for (int s = 1; s < NPB; s <<= 1) {
        int add = (t >= s) ? scanb[t - s] : 0;
        __syncthreads();
        scanb[t] += add;
        __syncthreads();
    }
    int off = scanb[t] - c;               // exclusive
    int node = (bkt << 8) + t;
    if (node < n_nodes) noff2[node] = make_int2((int)ebase + off, c);
    fill[t] = off;
    __syncthreads();

    for (int i = t; i < ecnt; i += 256) {
        unsigned v = pairs[ebase + i];
        int pos = atomicAdd(&fill[v & 255], 1);
        srcs[ebase + pos] = (int)(v >> 8);
    }
}

// ========== pull: out[n] = sum_{csr} z[src] + b2 (f32), 8-wide MLP ==========
__global__ __launch_bounds__(256) void pull_csr(
    const uint2* __restrict__ z2, const int* __restrict__ srcs,
    const int2* __restrict__ noff2, const float* __restrict__ b2,
    float* __restrict__ out, int n_nodes)
{
    int node = blockIdx.x * 8 + (threadIdx.x >> 5);
    int lane = threadIdx.x & 31;
    if (node >= n_nodes) return;
    int2 se = noff2[node];
    int i = se.x, end = se.x + se.y;

    float a0 = 0.f, a1 = 0.f, a2 = 0.f, a3 = 0.f;
    for (; i + 8 <= end; i += 8) {
        int4 sA = *(const int4*)(srcs + i);
        int4 sB = *(const int4*)(srcs + i + 4);
        uint2 v0 = z2[(size_t)sA.x * 32 + lane];
        uint2 v1 = z2[(size_t)sA.y * 32 + lane];
        uint2 v2 = z2[(size_t)sA.z * 32 + lane];
        uint2 v3 = z2[(size_t)sA.w * 32 + lane];
        uint2 v4 = z2[(size_t)sB.x * 32 + lane];
        uint2 v5 = z2[(size_t)sB.y * 32 + lane];
        uint2 v6 = z2[(size_t)sB.z * 32 + lane];
        uint2 v7 = z2[(size_t)sB.w * 32 + lane];
        a0 += bflo(v0.x) + bflo(v1.x) + bflo(v2.x) + bflo(v3.x)
            + bflo(v4.x) + bflo(v5.x) + bflo(v6.x) + bflo(v7.x);
        a1 += bfhi(v0.x) + bfhi(v1.x) + bfhi(v2.x) + bfhi(v3.x)
            + bfhi(v4.x) + bfhi(v5.x) + bfhi(v6.x) + bfhi(v7.x);
        a2 += bflo(v0.y) + bflo(v1.y) + bflo(v2.y) + bflo(v3.y)
            + bflo(v4.y) + bflo(v5.y) + bflo(v6.y) + bflo(v7.y);
        a3 += bfhi(v0.y) + bfhi(v1.y) + bfhi(v2.y) + bfhi(v3.y)
            + bfhi(v4.y) + bfhi(v5.y) + bfhi(v6.y) + bfhi(v7.y);
    }
    if (i + 4 <= end) {
        int4 s = *(const int4*)(srcs + i);
        uint2 v0 = z2[(size_t)s.x * 32 + lane];
        uint2 v1 = z2[(size_t)s.y * 32 + lane];
        uint2 v2 = z2[(size_t)s.z * 32 + lane];
        uint2 v3 = z2[(size_t)s.w * 32 + lane];
        a0 += bflo(v0.x) + bflo(v1.x) + bflo(v2.x) + bflo(v3.x);
        a1 += bfhi(v0.x) + bfhi(v1.x) + bfhi(v2.x) + bfhi(v3.x);
        a2 += bflo(v0.y) + bflo(v1.y) + bflo(v2.y) + bflo(v3.y);
        a3 += bfhi(v0.y) + bfhi(v1.y) + bfhi(v2.y) + bfhi(v3.y);
        i += 4;
    }
    for (; i < end; ++i) {
        int s = srcs[i];
        uint2 v = z2[(size_t)s * 32 + lane];
        a0 += bflo(v.x); a1 += bfhi(v.x);
        a2 += bflo(v.y); a3 += bfhi(v.y);
    }
    float4 bv = ((const float4*)b2)[lane];
    ((float4*)out)[(size_t)node * 32 + lane] =
        make_float4(a0 + bv.x, a1 + bv.y, a2 + bv.z, a3 + bv.w);
}

// Overflow edges (normally zero): out[d] += z[s], f32 atomics.
__global__ __launch_bounds__(32) void ovf_f32(
    const int* __restrict__ ovf_cnt, const int2* __restrict__ ovf_list,
    const uint2* __restrict__ z2, float* __restrict__ out)
{
    int n = *ovf_cnt;
    if (n > OVF_CAP) n = OVF_CAP;
    int lane = threadIdx.x;
    for (int i = blockIdx.x; i < n; i += gridDim.x) {
        int2 sd = ovf_list[i];
        uint2 v = z2[(size_t)sd.x * 32 + lane];
        unsafeAtomicAdd(&out[(size_t)sd.y * D + lane * 4 + 0], bflo(v.x));
        unsafeAtomicAdd(&out[(size_t)sd.y * D + lane * 4 + 1], bfhi(v.x));
        unsafeAtomicAdd(&out[(size_t)sd.y * D + lane * 4 + 2], bflo(v.y));
        unsafeAtomicAdd(&out[(size_t)sd.y * D + lane * 4 + 3], bfhi(v.y));
    }
}

// ================= fallback path (f32 atomic scatter) =================
template <bool RELU>
__global__ __launch_bounds__(256) void gemm_bias_act(
    const float* xin, const float* __restrict__ W,
    const float* __restrict__ b, float* xout, int n_rows)
{
    __shared__ float Ws[D * D];
    __shared__ float xs[32 * D];
    const int t = threadIdx.x;
    const int row0 = blockIdx.x * 32;
    const float4* Wv = (const float4*)W;
    float4* Wsv = (float4*)Ws;
#pragma unroll
    for (int i = 0; i < 16; ++i) Wsv[t + 256 * i] = Wv[t + 256 * i];
    const float4* xv = (const float4*)xin;
    float4* xsv = (float4*)xs;
#pragma unroll
    for (int i = 0; i < 4; ++i) {
        int f4 = t + 256 * i;
        int row = row0 + (f4 >> 5);
        if (row < n_rows) xsv[f4] = xv[(size_t)row0 * 32 + f4];
    }
    __syncthreads();
    const int cg = t & 31;
    const int rg = t >> 5;
    float4 bias = ((const float4*)b)[cg];
    float4 acc[4];
#pragma unroll
    for (int ri = 0; ri < 4; ++ri) acc[ri] = make_float4(0.f, 0.f, 0.f, 0.f);
#pragma unroll 4
    for (int k = 0; k < D; k += 4) {
        float4 w0 = Wsv[(k + 0) * 32 + cg];
        float4 w1 = Wsv[(k + 1) * 32 + cg];
        float4 w2 = Wsv[(k + 2) * 32 + cg];
        float4 w3 = Wsv[(k + 3) * 32 + cg];
#pragma unroll
        for (int ri = 0; ri < 4; ++ri) {
            float4 xa = xsv[(rg + 8 * ri) * 32 + (k >> 2)];
            acc[ri].x = fmaf(xa.x, w0.x, fmaf(xa.y, w1.x, fmaf(xa.z, w2.x, fmaf(xa.w, w3.x, acc[ri].x))));
            acc[ri].y = fmaf(xa.x, w0.y, fmaf(xa.y, w1.y, fmaf(xa.z, w2.y, fmaf(xa.w, w3.y, acc[ri].y))));
            acc[ri].z = fmaf(xa.x, w0.z, fmaf(xa.y, w1.z, fmaf(xa.z, w2.z, fmaf(xa.w, w3.z, acc[ri].z))));
            acc[ri].w = fmaf(xa.x, w0.w, fmaf(xa.y, w1.w, fmaf(xa.z, w2.w, fmaf(xa.w, w3.w, acc[ri].w))));
        }
    }
#pragma unroll
    for (int ri = 0; ri < 4; ++ri) {
        int row = row0 + rg + 8 * ri;
        if (row >= n_rows) continue;
        float4 o;
        o.x = acc[ri].x + bias.x; o.y = acc[ri].y + bias.y;
        o.z = acc[ri].z + bias.z; o.w = acc[ri].w + bias.w;
        if (RELU) {
            o.x = fmaxf(o.x, 0.f); o.y = fmaxf(o.y, 0.f);
            o.z = fmaxf(o.z, 0.f); o.w = fmaxf(o.w, 0.f);
        }
        ((float4*)xout)[(size_t)row * 32 + cg] = o;
    }
}

__global__ __launch_bounds__(256) void zero_kernel(float4* p, int n4)
{
    int i = blockIdx.x * 256 + threadIdx.x;
    int stride = gridDim.x * 256;
    for (; i < n4; i += stride) p[i] = make_float4(0.f, 0.f, 0.f, 0.f);
}

__global__ __launch_bounds__(256) void scatter_kernel(
    const float* __restrict__ h, const int* __restrict__ esrc,
    const int* __restrict__ edst, float* __restrict__ agg, long n_items)
{
    long idx = (long)blockIdx.x * 256 + threadIdx.x;
    long stride = (long)gridDim.x * 256;
    for (; idx < n_items; idx += stride) {
        int e = (int)(idx >> 7);
        int c = (int)(idx & 127);
        int s = esrc[e];
        int d = edst[e];
        unsafeAtomicAdd(&agg[(size_t)d * D + c], h[(size_t)s * D + c]);
    }
}

extern "C" void kernel_launch(void* const* d_in, const int* in_sizes, int n_in,
                              void* d_out, int out_size, void* d_ws, size_t ws_size,
                              hipStream_t stream)
{
    const float* x    = (const float*)d_in[0];
    const int*   esrc = (const int*)d_in[1];
    const int*   edst = (const int*)d_in[2];
    const float* W1   = (const float*)d_in[3];
    const float* b1   = (const float*)d_in[4];
    const float* W2   = (const float*)d_in[5];
    const float* b2   = (const float*)d_in[6];
    float* out = (float*)d_out;

    const int N = in_sizes[0] / D;   // 100000
    const int E = in_sizes[1];       // 1600000
    const int NB = (N + NPB - 1) / NPB;   // 391

    char* ws = (char*)d_ws;
    size_t off_z     = 0;                                        // z2: 25.6 MB
    size_t off_pairs = off_z + (size_t)N * 256;
    size_t off_srcs  = off_pairs + (size_t)NBMAX * BKCAP * 4;    // 16.8 MB
    size_t off_noff  = off_srcs + (size_t)NBMAX * BKCAP * 4;     // 16.8 MB
    size_t off_gfill = (off_noff + (size_t)N * 8 + 255) & ~(size_t)255;
    size_t off_ovfc  = off_gfill + NBMAX * 4;
    size_t off_ovfl  = off_ovfc + 16;
    size_t off_pack  = (off_ovfl + (size_t)OVF_CAP * 8 + 255) & ~(size_t)255;
    size_t need      = off_pack + 65536;

    const int gchunk = (E + CHUNK - 1) / CHUNK;   // 196
    const int nblk64 = (N + 63) / 64;             // 1563

    if (ws_size >= need && N <= NBMAX * NPB) {
        uint2*    z2    = (uint2*)(ws + off_z);
        unsigned* pairs = (unsigned*)(ws + off_pairs);
        int*      srcs  = (int*)(ws + off_srcs);
        int2*     noff2 = (int2*)(ws + off_noff);
        int*      gfill = (int*)(ws + off_gfill);
        int*      ovfc  = (int*)(ws + off_ovfc);
        int2*     ovfl  = (int2*)(ws + off_ovfl);
        uint4*    pack  = (uint4*)(ws + off_pack);

        hipMemsetAsync(gfill, 0, NBMAX * 4 + 16, stream);   // gfill + ovfc

        // 0) pack weights (needed by gemm blocks of the fused kernel)
        pack_w<<<16, 256, 0, stream>>>(W1, W2, pack);

        // 1) FUSED: edge bucketing (196 blocks) + z=relu(x@W1+b1)@W2 (1563)
        build_gemm<<<gchunk + nblk64, 256, 0, stream>>>(
            esrc, edst, gfill, pairs, ovfc, ovfl, E, NB, gchunk,
            x, pack, b1, (unsigned short*)z2, N);

        // 2) bucket pairs -> global CSR
        node_sort<<<NB, 256, 0, stream>>>(pairs, gfill, srcs, noff2, N);

        // 3) out[n] = sum z[src] + b2 (f32, 8-wide MLP gather)
        pull_csr<<<(N + 7) / 8, 256, 0, stream>>>(z2, srcs, noff2, b2, out, N);

        // 4) overflow edges (normally zero)
        ovf_f32<<<8, 32, 0, stream>>>(ovfc, ovfl, z2, out);
    } else {
        float* h = (float*)ws;
        const int nb32 = (N + 31) / 32;
        gemm_bias_act<true><<<nb32, 256, 0, stream>>>(x, W1, b1, h, N);
        zero_kernel<<<2048, 256, 0, stream>>>((float4*)out, N * D / 4);
        scatter_kernel<<<8192, 256, 0, stream>>>(h, esrc, edst, out, (long)E * D);
        gemm_bias_act<false><<<nb32, 256, 0, stream>>>(out, W2, b2, out, N);
    }
}

// Round 10
// 123.201 us; speedup vs baseline: 2.0989x; 1.0057x over previous
//
#include <hip/hip_runtime.h>

#define D 128
#define NPB 256            // nodes per bucket (dst>>8)
#define NBMAX 512          // max buckets (N <= 131072)
#define BKCAP 8192         // edge capacity per bucket (mean 4096, +64 sigma)
#define CHUNK 8192         // edges per scatter block
#define OVF_CAP 8192

typedef __attribute__((ext_vector_type(8))) short short8x;
typedef __attribute__((ext_vector_type(4))) float f32x4;

// ---- bf16 helpers (manual RNE) ----
__device__ inline unsigned int f2bf(float f) {
    unsigned int u = __builtin_bit_cast(unsigned int, f);
    return (u + 0x7fffu + ((u >> 16) & 1u)) >> 16;
}
__device__ inline float bflo(unsigned int v) {
    return __builtin_bit_cast(float, v << 16);
}
__device__ inline float bfhi(unsigned int v) {
    return __builtin_bit_cast(float, v & 0xffff0000u);
}
__device__ inline unsigned int pack2(float lo, float hi) {
    return f2bf(lo) | (f2bf(hi) << 16);
}

// ========= W pre-pack (+ block 16 zeroes gfill/ovfc — one fewer dispatch) ====
__global__ __launch_bounds__(256) void pack_w(
    const float* __restrict__ W1, const float* __restrict__ W2,
    uint4* __restrict__ pack, int* __restrict__ zero_area, int nz)
{
    if (blockIdx.x == 16) {
        for (int i = threadIdx.x; i < nz; i += 256) zero_area[i] = 0;
        return;
    }
    int e = blockIdx.x * 256 + threadIdx.x;      // 0..4095
    const float* W = (e & 2048) ? W2 : W1;
    int f = (e >> 6) & 31, l = e & 63;
    int kt = f >> 3, nt = f & 7;
    int k0 = kt * 32 + (l >> 4) * 8;
    int col = nt * 16 + (l & 15);
    unsigned int v[8];
#pragma unroll
    for (int j = 0; j < 8; ++j) v[j] = f2bf(W[(size_t)(k0 + j) * D + col]);
    uint4 o;
    o.x = v[0] | (v[1] << 16);
    o.y = v[2] | (v[3] << 16);
    o.z = v[4] | (v[5] << 16);
    o.w = v[6] | (v[7] << 16);
    pack[e] = o;
}

// ========== FUSED: bucket_scatter blocks + gemm blocks (independent) ========
__global__ __launch_bounds__(256) void build_gemm(
    const int* __restrict__ esrc, const int* __restrict__ edst,
    int* __restrict__ gfill, unsigned* __restrict__ pairs,
    int* __restrict__ ovf_cnt, int2* __restrict__ ovf_list, int E, int NB,
    int nscatter,
    const float* __restrict__ xin, const uint4* __restrict__ wpack,
    const float* __restrict__ b1, uint4* __restrict__ zout4, int n_rows)
{
    __shared__ __align__(16) char smem[81920];
    const int t = threadIdx.x;

    if (blockIdx.x < nscatter) {
        // ---------------- bucket scatter ----------------
        int* lcnt  = (int*)smem;
        int* lbase = lcnt + NBMAX;
        for (int b = t; b < NB; b += 256) lcnt[b] = 0;
        __syncthreads();
        int cb = blockIdx.x * CHUNK;
        int ce = min(E, cb + CHUNK);
        for (int i = cb + t; i < ce; i += 256)
            atomicAdd(&lcnt[edst[i] >> 8], 1);
        __syncthreads();
        for (int b = t; b < NB; b += 256) {
            int c = lcnt[b];
            lbase[b] = c ? atomicAdd(&gfill[b], c) : 0;
            lcnt[b] = 0;
        }
        __syncthreads();
        for (int i = cb + t; i < ce; i += 256) {
            int d = edst[i];
            int s = esrc[i];
            int b = d >> 8;
            int pos = lbase[b] + atomicAdd(&lcnt[b], 1);
            if (pos < BKCAP) {
                pairs[(size_t)b * BKCAP + pos] = ((unsigned)s << 8) | (unsigned)(d & 255);
            } else {
                int o = atomicAdd(ovf_cnt, 1);
                if (o < OVF_CAP) ovf_list[o] = make_int2(s, d);
            }
        }
        return;
    }

    // ---------------- fused GEMM: z = relu(x@W1+b1)@W2 ----------------
    uint4* ws1 = (uint4*)smem;          // 32KB (reused as z staging later)
    uint4* ws2 = ws1 + 2048;            // 32KB
    uint4* xs4 = ws2 + 2048;            // 16KB (64 rows x 16 uint4, swizzled)
    const int row0 = (blockIdx.x - nscatter) * 64;

#pragma unroll
    for (int i = 0; i < 8; ++i) ws1[t + 256 * i] = wpack[t + 256 * i];
#pragma unroll
    for (int i = 0; i < 8; ++i) ws2[t + 256 * i] = wpack[2048 + t + 256 * i];

    const float4* g = (const float4*)xin;
#pragma unroll
    for (int i = 0; i < 4; ++i) {
        int c = t + 256 * i;              // 0..1023
        int row = c >> 4, kc = c & 15;
        int grow = row0 + row;
        if (grow < n_rows) {
            float4 f0 = g[(size_t)grow * 32 + kc * 2];
            float4 f1 = g[(size_t)grow * 32 + kc * 2 + 1];
            uint4 v;
            v.x = pack2(f0.x, f0.y);
            v.y = pack2(f0.z, f0.w);
            v.z = pack2(f1.x, f1.y);
            v.w = pack2(f1.z, f1.w);
            xs4[row * 16 + (kc ^ (row & 7))] = v;
        }
    }
    __syncthreads();

    const int l = t & 63;
    const int w = t >> 6;
    const int l15 = l & 15;
    const int lk = l >> 4;
    const int arow = w * 16 + l15;

    float bias1[8];
#pragma unroll
    for (int nt = 0; nt < 8; ++nt) bias1[nt] = b1[nt * 16 + l15];

    f32x4 acc1[8];
#pragma unroll
    for (int nt = 0; nt < 8; ++nt) acc1[nt] = (f32x4){0.f, 0.f, 0.f, 0.f};

#pragma unroll
    for (int kt = 0; kt < 4; ++kt) {
        short8x a = *(const short8x*)&xs4[arow * 16 + ((kt * 4 + lk) ^ (arow & 7))];
#pragma unroll
        for (int nt = 0; nt < 8; ++nt) {
            short8x bf = *(const short8x*)&ws1[(kt * 8 + nt) * 64 + l];
            acc1[nt] = __builtin_amdgcn_mfma_f32_16x16x32_bf16(a, bf, acc1[nt], 0, 0, 0);
        }
    }
    __syncthreads();   // xs reads done -> overwrite with h; ws1 reads done too

    // h = relu(acc1 + b1), bf16, same swizzle. D layout: col=l&15, row=lk*4+r
    unsigned short* hsu = (unsigned short*)xs4;
#pragma unroll
    for (int nt = 0; nt < 8; ++nt) {
        int col = nt * 16 + l15;
        int ci = (col >> 3), ce2 = (col & 7);
#pragma unroll
        for (int r = 0; r < 4; ++r) {
            int rowl = w * 16 + lk * 4 + r;
            float v = fmaxf(acc1[nt][r] + bias1[nt], 0.f);
            hsu[(rowl * 16 + (ci ^ (rowl & 7))) * 8 + ce2] = (unsigned short)f2bf(v);
        }
    }
    __syncthreads();

    f32x4 acc2[8];
#pragma unroll
    for (int nt = 0; nt < 8; ++nt) acc2[nt] = (f32x4){0.f, 0.f, 0.f, 0.f};

#pragma unroll
    for (int kt = 0; kt < 4; ++kt) {
        short8x a = *(const short8x*)&xs4[arow * 16 + ((kt * 4 + lk) ^ (arow & 7))];
#pragma unroll
        for (int nt = 0; nt < 8; ++nt) {
            short8x bf = *(const short8x*)&ws2[(kt * 8 + nt) * 64 + l];
            acc2[nt] = __builtin_amdgcn_mfma_f32_16x16x32_bf16(a, bf, acc2[nt], 0, 0, 0);
        }
    }

    // Stage z tile (bf16, standard [64][128] layout) into ws1 (dead), then
    // store fully coalesced uint4s. (Was: 32 scattered 2B stores/thread.)
    unsigned short* zls = (unsigned short*)ws1;   // 16KB used
#pragma unroll
    for (int nt = 0; nt < 8; ++nt) {
        int col = nt * 16 + l15;
#pragma unroll
        for (int r = 0; r < 4; ++r) {
            int rowl = w * 16 + lk * 4 + r;
            zls[rowl * D + col] = (unsigned short)f2bf(acc2[nt][r]);
        }
    }
    __syncthreads();
    const uint4* zlsv = (const uint4*)zls;
#pragma unroll
    for (int i = 0; i < 4; ++i) {
        int c = t + 256 * i;              // 0..1023
        int row = c >> 4, kc = c & 15;
        if (row0 + row < n_rows)
            zout4[(size_t)(row0 + row) * 16 + kc] = zlsv[c];
    }
}

// ========== node sort: bucket pairs -> global CSR (srcs + (start,count)) ====
__global__ __launch_bounds__(256) void node_sort(
    const unsigned* __restrict__ pairs, const int* __restrict__ gfill,
    int* __restrict__ srcs, int2* __restrict__ noff2, int n_nodes)
{
    __shared__ int fill[NPB];
    __shared__ int scanb[NPB];
    const int bkt = blockIdx.x;
    const int t = threadIdx.x;
    const size_t ebase = (size_t)bkt * BKCAP;
    const int ecnt = min(gfill[bkt], BKCAP);

    fill[t] = 0;
    __syncthreads();
    for (int i = t; i < ecnt; i += 256)
        atomicAdd(&fill[pairs[ebase + i] & 255], 1);
    __syncthreads();

    int c = fill[t];
    scanb[t] = c;
    __syncthreads();
    for (int s = 1; s < NPB; s <<= 1) {
        int add = (t >= s) ? scanb[t - s] : 0;
        __syncthreads();
        scanb[t] += add;
        __syncthreads();
    }
    int off = scanb[t] - c;               // exclusive
    int node = (bkt << 8) + t;
    if (node < n_nodes) noff2[node] = make_int2((int)ebase + off, c);
    fill[t] = off;
    __syncthreads();

    for (int i = t; i < ecnt; i += 256) {
        unsigned v = pairs[ebase + i];
        int pos = atomicAdd(&fill[v & 255], 1);
        srcs[ebase + pos] = (int)(v >> 8);
    }
}

// ========== pull: out[n] = sum_{csr} z[src] + b2 (f32) ======================
// 16 lanes/node (uint4 = 16B/lane per row), 16 nodes/block, 8-deep MLP.
__global__ __launch_bounds__(256) void pull_csr(
    const uint4* __restrict__ z4, const int* __restrict__ srcs,
    const int2* __restrict__ noff2, const float* __restrict__ b2,
    float* __restrict__ out, int n_nodes)
{
    int node = blockIdx.x * 16 + (threadIdx.x >> 4);
    int lane = threadIdx.x & 15;
    if (node >= n_nodes) return;
    int2 se = noff2[node];
    int i = se.x, end = se.x + se.y;

    float a0 = 0.f, a1 = 0.f, a2 = 0.f, a3 = 0.f;
    float a4 = 0.f, a5 = 0.f, a6 = 0.f, a7 = 0.f;

#define ACC8(v) do { \
        a0 += bflo((v).x); a1 += bfhi((v).x); \
        a2 += bflo((v).y); a3 += bfhi((v).y); \
        a4 += bflo((v).z); a5 += bfhi((v).z); \
        a6 += bflo((v).w); a7 += bfhi((v).w); } while (0)

    for (; i + 8 <= end; i += 8) {
        int4 sA = *(const int4*)(srcs + i);
        int4 sB = *(const int4*)(srcs + i + 4);
        uint4 v0 = z4[(size_t)sA.x * 16 + lane];
        uint4 v1 = z4[(size_t)sA.y * 16 + lane];
        uint4 v2 = z4[(size_t)sA.z * 16 + lane];
        uint4 v3 = z4[(size_t)sA.w * 16 + lane];
        uint4 v4 = z4[(size_t)sB.x * 16 + lane];
        uint4 v5 = z4[(size_t)sB.y * 16 + lane];
        uint4 v6 = z4[(size_t)sB.z * 16 + lane];
        uint4 v7 = z4[(size_t)sB.w * 16 + lane];
        ACC8(v0); ACC8(v1); ACC8(v2); ACC8(v3);
        ACC8(v4); ACC8(v5); ACC8(v6); ACC8(v7);
    }
    if (i + 4 <= end) {
        int4 s = *(const int4*)(srcs + i);
        uint4 v0 = z4[(size_t)s.x * 16 + lane];
        uint4 v1 = z4[(size_t)s.y * 16 + lane];
        uint4 v2 = z4[(size_t)s.z * 16 + lane];
        uint4 v3 = z4[(size_t)s.w * 16 + lane];
        ACC8(v0); ACC8(v1); ACC8(v2); ACC8(v3);
        i += 4;
    }
    for (; i < end; ++i) {
        uint4 v = z4[(size_t)srcs[i] * 16 + lane];
        ACC8(v);
    }
#undef ACC8

    float4 bv0 = ((const float4*)b2)[lane * 2];
    float4 bv1 = ((const float4*)b2)[lane * 2 + 1];
    float4* op = (float4*)out + (size_t)node * 32 + lane * 2;
    op[0] = make_float4(a0 + bv0.x, a1 + bv0.y, a2 + bv0.z, a3 + bv0.w);
    op[1] = make_float4(a4 + bv1.x, a5 + bv1.y, a6 + bv1.z, a7 + bv1.w);
}

// Overflow edges (normally zero): out[d] += z[s], f32 atomics.
__global__ __launch_bounds__(32) void ovf_f32(
    const int* __restrict__ ovf_cnt, const int2* __restrict__ ovf_list,
    const uint2* __restrict__ z2, float* __restrict__ out)
{
    int n = *ovf_cnt;
    if (n > OVF_CAP) n = OVF_CAP;
    int lane = threadIdx.x;
    for (int i = blockIdx.x; i < n; i += gridDim.x) {
        int2 sd = ovf_list[i];
        uint2 v = z2[(size_t)sd.x * 32 + lane];
        unsafeAtomicAdd(&out[(size_t)sd.y * D + lane * 4 + 0], bflo(v.x));
        unsafeAtomicAdd(&out[(size_t)sd.y * D + lane * 4 + 1], bfhi(v.x));
        unsafeAtomicAdd(&out[(size_t)sd.y * D + lane * 4 + 2], bflo(v.y));
        unsafeAtomicAdd(&out[(size_t)sd.y * D + lane * 4 + 3], bfhi(v.y));
    }
}

// ================= fallback path (f32 atomic scatter) =================
template <bool RELU>
__global__ __launch_bounds__(256) void gemm_bias_act(
    const float* xin, const float* __restrict__ W,
    const float* __restrict__ b, float* xout, int n_rows)
{
    __shared__ float Ws[D * D];
    __shared__ float xs[32 * D];
    const int t = threadIdx.x;
    const int row0 = blockIdx.x * 32;
    const float4* Wv = (const float4*)W;
    float4* Wsv = (float4*)Ws;
#pragma unroll
    for (int i = 0; i < 16; ++i) Wsv[t + 256 * i] = Wv[t + 256 * i];
    const float4* xv = (const float4*)xin;
    float4* xsv = (float4*)xs;
#pragma unroll
    for (int i = 0; i < 4; ++i) {
        int f4 = t + 256 * i;
        int row = row0 + (f4 >> 5);
        if (row < n_rows) xsv[f4] = xv[(size_t)row0 * 32 + f4];
    }
    __syncthreads();
    const int cg = t & 31;
    const int rg = t >> 5;
    float4 bias = ((const float4*)b)[cg];
    float4 acc[4];
#pragma unroll
    for (int ri = 0; ri < 4; ++ri) acc[ri] = make_float4(0.f, 0.f, 0.f, 0.f);
#pragma unroll 4
    for (int k = 0; k < D; k += 4) {
        float4 w0 = Wsv[(k + 0) * 32 + cg];
        float4 w1 = Wsv[(k + 1) * 32 + cg];
        float4 w2 = Wsv[(k + 2) * 32 + cg];
        float4 w3 = Wsv[(k + 3) * 32 + cg];
#pragma unroll
        for (int ri = 0; ri < 4; ++ri) {
            float4 xa = xsv[(rg + 8 * ri) * 32 + (k >> 2)];
            acc[ri].x = fmaf(xa.x, w0.x, fmaf(xa.y, w1.x, fmaf(xa.z, w2.x, fmaf(xa.w, w3.x, acc[ri].x))));
            acc[ri].y = fmaf(xa.x, w0.y, fmaf(xa.y, w1.y, fmaf(xa.z, w2.y, fmaf(xa.w, w3.y, acc[ri].y))));
            acc[ri].z = fmaf(xa.x, w0.z, fmaf(xa.y, w1.z, fmaf(xa.z, w2.z, fmaf(xa.w, w3.z, acc[ri].z))));
            acc[ri].w = fmaf(xa.x, w0.w, fmaf(xa.y, w1.w, fmaf(xa.z, w2.w, fmaf(xa.w, w3.w, acc[ri].w))));
        }
    }
#pragma unroll
    for (int ri = 0; ri < 4; ++ri) {
        int row = row0 + rg + 8 * ri;
        if (row >= n_rows) continue;
        float4 o;
        o.x = acc[ri].x + bias.x; o.y = acc[ri].y + bias.y;
        o.z = acc[ri].z + bias.z; o.w = acc[ri].w + bias.w;
        if (RELU) {
            o.x = fmaxf(o.x, 0.f); o.y = fmaxf(o.y, 0.f);
            o.z = fmaxf(o.z, 0.f); o.w = fmaxf(o.w, 0.f);
        }
        ((float4*)xout)[(size_t)row * 32 + cg] = o;
    }
}

__global__ __launch_bounds__(256) void zero_kernel(float4* p, int n4)
{
    int i = blockIdx.x * 256 + threadIdx.x;
    int stride = gridDim.x * 256;
    for (; i < n4; i += stride) p[i] = make_float4(0.f, 0.f, 0.f, 0.f);
}

__global__ __launch_bounds__(256) void scatter_kernel(
    const float* __restrict__ h, const int* __restrict__ esrc,
    const int* __restrict__ edst, float* __restrict__ agg, long n_items)
{
    long idx = (long)blockIdx.x * 256 + threadIdx.x;
    long stride = (long)gridDim.x * 256;
    for (; idx < n_items; idx += stride) {
        int e = (int)(idx >> 7);
        int c = (int)(idx & 127);
        int s = esrc[e];
        int d = edst[e];
        unsafeAtomicAdd(&agg[(size_t)d * D + c], h[(size_t)s * D + c]);
    }
}

extern "C" void kernel_launch(void* const* d_in, const int* in_sizes, int n_in,
                              void* d_out, int out_size, void* d_ws, size_t ws_size,
                              hipStream_t stream)
{
    const float* x    = (const float*)d_in[0];
    const int*   esrc = (const int*)d_in[1];
    const int*   edst = (const int*)d_in[2];
    const float* W1   = (const float*)d_in[3];
    const float* b1   = (const float*)d_in[4];
    const float* W2   = (const float*)d_in[5];
    const float* b2   = (const float*)d_in[6];
    float* out = (float*)d_out;

    const int N = in_sizes[0] / D;   // 100000
    const int E = in_sizes[1];       // 1600000
    const int NB = (N + NPB - 1) / NPB;   // 391

    char* ws = (char*)d_ws;
    size_t off_z     = 0;                                        // z: 25.6 MB
    size_t off_pairs = off_z + (size_t)N * 256;
    size_t off_srcs  = off_pairs + (size_t)NBMAX * BKCAP * 4;    // 16.8 MB
    size_t off_noff  = off_srcs + (size_t)NBMAX * BKCAP * 4;     // 16.8 MB
    size_t off_gfill = (off_noff + (size_t)N * 8 + 255) & ~(size_t)255;
    size_t off_ovfc  = off_gfill + NBMAX * 4;
    size_t off_ovfl  = off_ovfc + 16;
    size_t off_pack  = (off_ovfl + (size_t)OVF_CAP * 8 + 255) & ~(size_t)255;
    size_t need      = off_pack + 65536;

    const int gchunk = (E + CHUNK - 1) / CHUNK;   // 196
    const int nblk64 = (N + 63) / 64;             // 1563

    if (ws_size >= need && N <= NBMAX * NPB) {
        uint4*    z4    = (uint4*)(ws + off_z);
        unsigned* pairs = (unsigned*)(ws + off_pairs);
        int*      srcs  = (int*)(ws + off_srcs);
        int2*     noff2 = (int2*)(ws + off_noff);
        int*      gfill = (int*)(ws + off_gfill);
        int*      ovfc  = (int*)(ws + off_ovfc);
        int2*     ovfl  = (int2*)(ws + off_ovfl);
        uint4*    pack  = (uint4*)(ws + off_pack);

        // 0) pack weights; block 16 zeroes gfill+ovfc (NBMAX+4 ints)
        pack_w<<<17, 256, 0, stream>>>(W1, W2, pack, gfill, NBMAX + 4);

        // 1) FUSED: edge bucketing (196 blocks) + z=relu(x@W1+b1)@W2 (1563)
        build_gemm<<<gchunk + nblk64, 256, 0, stream>>>(
            esrc, edst, gfill, pairs, ovfc, ovfl, E, NB, gchunk,
            x, pack, b1, z4, N);

        // 2) bucket pairs -> global CSR
        node_sort<<<NB, 256, 0, stream>>>(pairs, gfill, srcs, noff2, N);

        // 3) out[n] = sum z[src] + b2 (f32, 16-lane uint4 gather, 8-deep MLP)
        pull_csr<<<(N + 15) / 16, 256, 0, stream>>>(z4, srcs, noff2, b2, out, N);

        // 4) overflow edges (normally zero)
        ovf_f32<<<8, 32, 0, stream>>>(ovfc, ovfl, (const uint2*)z4, out);
    } else {
        float* h = (float*)ws;
        const int nb32 = (N + 31) / 32;
        gemm_bias_act<true><<<nb32, 256, 0, stream>>>(x, W1, b1, h, N);
        zero_kernel<<<2048, 256, 0, stream>>>((float4*)out, N * D / 4);
        scatter_kernel<<<8192, 256, 0, stream>>>(h, esrc, edst, out, (long)E * D);
        gemm_bias_act<false><<<nb32, 256, 0, stream>>>(out, W2, b2, out, N);
    }
}

// Round 11
// 121.181 us; speedup vs baseline: 2.1338x; 1.0167x over previous
//
#include <hip/hip_runtime.h>

#define D 128
#define NPB 256            // nodes per bucket (dst>>8)
#define NBMAX 512          // max buckets (N <= 131072)
#define BKCAP 8192         // edge capacity per bucket (mean 4096, +64 sigma)
#define CHUNK 8192         // edges per scatter block
#define OVF_CAP 8192

typedef __attribute__((ext_vector_type(8))) short short8x;
typedef __attribute__((ext_vector_type(4))) float f32x4;

// ---- bf16 helpers (manual RNE) ----
__device__ inline unsigned int f2bf(float f) {
    unsigned int u = __builtin_bit_cast(unsigned int, f);
    return (u + 0x7fffu + ((u >> 16) & 1u)) >> 16;
}
__device__ inline float bflo(unsigned int v) {
    return __builtin_bit_cast(float, v << 16);
}
__device__ inline float bfhi(unsigned int v) {
    return __builtin_bit_cast(float, v & 0xffff0000u);
}
__device__ inline unsigned int pack2(float lo, float hi) {
    return f2bf(lo) | (f2bf(hi) << 16);
}

// ========= W pre-pack (+ block 16 zeroes gfill/ovfc — one fewer dispatch) ====
__global__ __launch_bounds__(256) void pack_w(
    const float* __restrict__ W1, const float* __restrict__ W2,
    uint4* __restrict__ pack, int* __restrict__ zero_area, int nz)
{
    if (blockIdx.x == 16) {
        for (int i = threadIdx.x; i < nz; i += 256) zero_area[i] = 0;
        return;
    }
    int e = blockIdx.x * 256 + threadIdx.x;      // 0..4095
    const float* W = (e & 2048) ? W2 : W1;
    int f = (e >> 6) & 31, l = e & 63;
    int kt = f >> 3, nt = f & 7;
    int k0 = kt * 32 + (l >> 4) * 8;
    int col = nt * 16 + (l & 15);
    unsigned int v[8];
#pragma unroll
    for (int j = 0; j < 8; ++j) v[j] = f2bf(W[(size_t)(k0 + j) * D + col]);
    uint4 o;
    o.x = v[0] | (v[1] << 16);
    o.y = v[2] | (v[3] << 16);
    o.z = v[4] | (v[5] << 16);
    o.w = v[6] | (v[7] << 16);
    pack[e] = o;
}

// ========== FUSED: bucket_scatter blocks + gemm blocks (independent) ========
// gemm path: 128-row tile, sequential W1/W2 staging in one 32KB buffer,
// 4 waves x 32 rows, 64 MFMA per wave per GEMM. LDS 64KB -> 2 blocks/CU.
__global__ __launch_bounds__(256) void build_gemm(
    const int* __restrict__ esrc, const int* __restrict__ edst,
    int* __restrict__ gfill, unsigned* __restrict__ pairs,
    int* __restrict__ ovf_cnt, int2* __restrict__ ovf_list, int E, int NB,
    int nscatter,
    const float* __restrict__ xin, const uint4* __restrict__ wpack,
    const float* __restrict__ b1, uint4* __restrict__ zout4, int n_rows)
{
    __shared__ __align__(16) char smem[65536];
    const int t = threadIdx.x;

    if (blockIdx.x < nscatter) {
        // ---------------- bucket scatter ----------------
        int* lcnt  = (int*)smem;
        int* lbase = lcnt + NBMAX;
        for (int b = t; b < NB; b += 256) lcnt[b] = 0;
        __syncthreads();
        int cb = blockIdx.x * CHUNK;
        int ce = min(E, cb + CHUNK);
        for (int i = cb + t; i < ce; i += 256)
            atomicAdd(&lcnt[edst[i] >> 8], 1);
        __syncthreads();
        for (int b = t; b < NB; b += 256) {
            int c = lcnt[b];
            lbase[b] = c ? atomicAdd(&gfill[b], c) : 0;
            lcnt[b] = 0;
        }
        __syncthreads();
        for (int i = cb + t; i < ce; i += 256) {
            int d = edst[i];
            int s = esrc[i];
            int b = d >> 8;
            int pos = lbase[b] + atomicAdd(&lcnt[b], 1);
            if (pos < BKCAP) {
                pairs[(size_t)b * BKCAP + pos] = ((unsigned)s << 8) | (unsigned)(d & 255);
            } else {
                int o = atomicAdd(ovf_cnt, 1);
                if (o < OVF_CAP) ovf_list[o] = make_int2(s, d);
            }
        }
        return;
    }

    // ---------------- fused GEMM: z = relu(x@W1+b1)@W2, 128 rows ------------
    uint4* ws  = (uint4*)smem;          // 32KB: W1, then W2, then z staging
    uint4* xs4 = ws + 2048;             // 32KB: 128 rows x 16 uint4, swizzled
    const int row0 = (blockIdx.x - nscatter) * 128;

    // stage W1 + x tile
#pragma unroll
    for (int i = 0; i < 8; ++i) ws[t + 256 * i] = wpack[t + 256 * i];

    const float4* g = (const float4*)xin;
#pragma unroll
    for (int i = 0; i < 8; ++i) {
        int c = t + 256 * i;              // 0..2047
        int row = c >> 4, kc = c & 15;
        int grow = row0 + row;
        if (grow < n_rows) {
            float4 f0 = g[(size_t)grow * 32 + kc * 2];
            float4 f1 = g[(size_t)grow * 32 + kc * 2 + 1];
            uint4 v;
            v.x = pack2(f0.x, f0.y);
            v.y = pack2(f0.z, f0.w);
            v.z = pack2(f1.x, f1.y);
            v.w = pack2(f1.z, f1.w);
            xs4[row * 16 + (kc ^ (row & 7))] = v;
        }
    }
    __syncthreads();

    const int l = t & 63;
    const int w = t >> 6;
    const int l15 = l & 15;
    const int lk = l >> 4;
    const int arow0 = w * 32 + l15;       // rows w*32..+15
    const int arow1 = arow0 + 16;         // rows w*32+16..+31

    float bias1[8];
#pragma unroll
    for (int nt = 0; nt < 8; ++nt) bias1[nt] = b1[nt * 16 + l15];

    f32x4 acc1[2][8];
#pragma unroll
    for (int rt = 0; rt < 2; ++rt)
#pragma unroll
        for (int nt = 0; nt < 8; ++nt) acc1[rt][nt] = (f32x4){0.f, 0.f, 0.f, 0.f};

#pragma unroll
    for (int kt = 0; kt < 4; ++kt) {
        int kc0 = kt * 4 + lk;
        short8x a0 = *(const short8x*)&xs4[arow0 * 16 + (kc0 ^ (arow0 & 7))];
        short8x a1 = *(const short8x*)&xs4[arow1 * 16 + (kc0 ^ (arow1 & 7))];
#pragma unroll
        for (int nt = 0; nt < 8; ++nt) {
            short8x bf = *(const short8x*)&ws[(kt * 8 + nt) * 64 + l];
            acc1[0][nt] = __builtin_amdgcn_mfma_f32_16x16x32_bf16(a0, bf, acc1[0][nt], 0, 0, 0);
            acc1[1][nt] = __builtin_amdgcn_mfma_f32_16x16x32_bf16(a1, bf, acc1[1][nt], 0, 0, 0);
        }
    }

    // h = relu(acc1+b1) -> overwrite xs rows (wave-private rows, no barrier
    // needed for xs; barrier below protects ws). D layout: col=l&15, row=lk*4+r
    unsigned short* hsu = (unsigned short*)xs4;
#pragma unroll
    for (int rt = 0; rt < 2; ++rt) {
#pragma unroll
        for (int nt = 0; nt < 8; ++nt) {
            int col = nt * 16 + l15;
            int ci = (col >> 3), ce2 = (col & 7);
#pragma unroll
            for (int r = 0; r < 4; ++r) {
                int rowl = w * 32 + rt * 16 + lk * 4 + r;
                float v = fmaxf(acc1[rt][nt][r] + bias1[nt], 0.f);
                hsu[(rowl * 16 + (ci ^ (rowl & 7))) * 8 + ce2] = (unsigned short)f2bf(v);
            }
        }
    }
    __syncthreads();   // all waves' W1 reads done -> overwrite ws with W2

#pragma unroll
    for (int i = 0; i < 8; ++i) ws[t + 256 * i] = wpack[2048 + t + 256 * i];
    __syncthreads();

    f32x4 acc2[2][8];
#pragma unroll
    for (int rt = 0; rt < 2; ++rt)
#pragma unroll
        for (int nt = 0; nt < 8; ++nt) acc2[rt][nt] = (f32x4){0.f, 0.f, 0.f, 0.f};

#pragma unroll
    for (int kt = 0; kt < 4; ++kt) {
        int kc0 = kt * 4 + lk;
        short8x a0 = *(const short8x*)&xs4[arow0 * 16 + (kc0 ^ (arow0 & 7))];
        short8x a1 = *(const short8x*)&xs4[arow1 * 16 + (kc0 ^ (arow1 & 7))];
#pragma unroll
        for (int nt = 0; nt < 8; ++nt) {
            short8x bf = *(const short8x*)&ws[(kt * 8 + nt) * 64 + l];
            acc2[0][nt] = __builtin_amdgcn_mfma_f32_16x16x32_bf16(a0, bf, acc2[0][nt], 0, 0, 0);
            acc2[1][nt] = __builtin_amdgcn_mfma_f32_16x16x32_bf16(a1, bf, acc2[1][nt], 0, 0, 0);
        }
    }
    __syncthreads();   // all waves' W2 reads done -> ws becomes z staging

    // stage z tile (bf16 [128][128]) into ws, then coalesced uint4 store
    unsigned short* zls = (unsigned short*)ws;
#pragma unroll
    for (int rt = 0; rt < 2; ++rt) {
#pragma unroll
        for (int nt = 0; nt < 8; ++nt) {
            int col = nt * 16 + l15;
#pragma unroll
            for (int r = 0; r < 4; ++r) {
                int rowl = w * 32 + rt * 16 + lk * 4 + r;
                zls[rowl * D + col] = (unsigned short)f2bf(acc2[rt][nt][r]);
            }
        }
    }
    __syncthreads();
    const uint4* zlsv = (const uint4*)zls;
#pragma unroll
    for (int i = 0; i < 8; ++i) {
        int c = t + 256 * i;              // 0..2047
        int row = c >> 4, kc = c & 15;
        if (row0 + row < n_rows)
            zout4[(size_t)(row0 + row) * 16 + kc] = zlsv[c];
    }
}

// ========== node sort: bucket pairs -> global CSR (srcs + (start,count)) ====
__global__ __launch_bounds__(256) void node_sort(
    const unsigned* __restrict__ pairs, const int* __restrict__ gfill,
    int* __restrict__ srcs, int2* __restrict__ noff2, int n_nodes)
{
    __shared__ int fill[NPB];
    __shared__ int scanb[NPB];
    const int bkt = blockIdx.x;
    const int t = threadIdx.x;
    const size_t ebase = (size_t)bkt * BKCAP;
    const int ecnt = min(gfill[bkt], BKCAP);

    fill[t] = 0;
    __syncthreads();
    for (int i = t; i < ecnt; i += 256)
        atomicAdd(&fill[pairs[ebase + i] & 255], 1);
    __syncthreads();

    int c = fill[t];
    scanb[t] = c;
    __syncthreads();
    for (int s = 1; s < NPB; s <<= 1) {
        int add = (t >= s) ? scanb[t - s] : 0;
        __syncthreads();
        scanb[t] += add;
        __syncthreads();
    }
    int off = scanb[t] - c;               // exclusive
    int node = (bkt << 8) + t;
    if (node < n_nodes) noff2[node] = make_int2((int)ebase + off, c);
    fill[t] = off;
    __syncthreads();

    for (int i = t; i < ecnt; i += 256) {
        unsigned v = pairs[ebase + i];
        int pos = atomicAdd(&fill[v & 255], 1);
        srcs[ebase + pos] = (int)(v >> 8);
    }
}

// ========== pull: out[n] = sum_{csr} z[src] + b2 (f32), 8-wide MLP ==========
// 32 lanes/node (uint2/lane), 8 nodes/block — R9 shape (70% occ, best measured)
__global__ __launch_bounds__(256) void pull_csr(
    const uint2* __restrict__ z2, const int* __restrict__ srcs,
    const int2* __restrict__ noff2, const float* __restrict__ b2,
    float* __restrict__ out, int n_nodes)
{
    int node = blockIdx.x * 8 + (threadIdx.x >> 5);
    int lane = threadIdx.x & 31;
    if (node >= n_nodes) return;
    int2 se = noff2[node];
    int i = se.x, end = se.x + se.y;

    float a0 = 0.f, a1 = 0.f, a2 = 0.f, a3 = 0.f;
    for (; i + 8 <= end; i += 8) {
        int4 sA = *(const int4*)(srcs + i);
        int4 sB = *(const int4*)(srcs + i + 4);
        uint2 v0 = z2[(size_t)sA.x * 32 + lane];
        uint2 v1 = z2[(size_t)sA.y * 32 + lane];
        uint2 v2 = z2[(size_t)sA.z * 32 + lane];
        uint2 v3 = z2[(size_t)sA.w * 32 + lane];
        uint2 v4 = z2[(size_t)sB.x * 32 + lane];
        uint2 v5 = z2[(size_t)sB.y * 32 + lane];
        uint2 v6 = z2[(size_t)sB.z * 32 + lane];
        uint2 v7 = z2[(size_t)sB.w * 32 + lane];
        a0 += bflo(v0.x) + bflo(v1.x) + bflo(v2.x) + bflo(v3.x)
            + bflo(v4.x) + bflo(v5.x) + bflo(v6.x) + bflo(v7.x);
        a1 += bfhi(v0.x) + bfhi(v1.x) + bfhi(v2.x) + bfhi(v3.x)
            + bfhi(v4.x) + bfhi(v5.x) + bfhi(v6.x) + bfhi(v7.x);
        a2 += bflo(v0.y) + bflo(v1.y) + bflo(v2.y) + bflo(v3.y)
            + bflo(v4.y) + bflo(v5.y) + bflo(v6.y) + bflo(v7.y);
        a3 += bfhi(v0.y) + bfhi(v1.y) + bfhi(v2.y) + bfhi(v3.y)
            + bfhi(v4.y) + bfhi(v5.y) + bfhi(v6.y) + bfhi(v7.y);
    }
    if (i + 4 <= end) {
        int4 s = *(const int4*)(srcs + i);
        uint2 v0 = z2[(size_t)s.x * 32 + lane];
        uint2 v1 = z2[(size_t)s.y * 32 + lane];
        uint2 v2 = z2[(size_t)s.z * 32 + lane];
        uint2 v3 = z2[(size_t)s.w * 32 + lane];
        a0 += bflo(v0.x) + bflo(v1.x) + bflo(v2.x) + bflo(v3.x);
        a1 += bfhi(v0.x) + bfhi(v1.x) + bfhi(v2.x) + bfhi(v3.x);
        a2 += bflo(v0.y) + bflo(v1.y) + bflo(v2.y) + bflo(v3.y);
        a3 += bfhi(v0.y) + bfhi(v1.y) + bfhi(v2.y) + bfhi(v3.y);
        i += 4;
    }
    for (; i < end; ++i) {
        int s = srcs[i];
        uint2 v = z2[(size_t)s * 32 + lane];
        a0 += bflo(v.x); a1 += bfhi(v.x);
        a2 += bflo(v.y); a3 += bfhi(v.y);
    }
    float4 bv = ((const float4*)b2)[lane];
    ((float4*)out)[(size_t)node * 32 + lane] =
        make_float4(a0 + bv.x, a1 + bv.y, a2 + bv.z, a3 + bv.w);
}

// Overflow edges (normally zero): out[d] += z[s], f32 atomics.
__global__ __launch_bounds__(32) void ovf_f32(
    const int* __restrict__ ovf_cnt, const int2* __restrict__ ovf_list,
    const uint2* __restrict__ z2, float* __restrict__ out)
{
    int n = *ovf_cnt;
    if (n > OVF_CAP) n = OVF_CAP;
    int lane = threadIdx.x;
    for (int i = blockIdx.x; i < n; i += gridDim.x) {
        int2 sd = ovf_list[i];
        uint2 v = z2[(size_t)sd.x * 32 + lane];
        unsafeAtomicAdd(&out[(size_t)sd.y * D + lane * 4 + 0], bflo(v.x));
        unsafeAtomicAdd(&out[(size_t)sd.y * D + lane * 4 + 1], bfhi(v.x));
        unsafeAtomicAdd(&out[(size_t)sd.y * D + lane * 4 + 2], bflo(v.y));
        unsafeAtomicAdd(&out[(size_t)sd.y * D + lane * 4 + 3], bfhi(v.y));
    }
}

// ================= fallback path (f32 atomic scatter) =================
template <bool RELU>
__global__ __launch_bounds__(256) void gemm_bias_act(
    const float* xin, const float* __restrict__ W,
    const float* __restrict__ b, float* xout, int n_rows)
{
    __shared__ float Ws[D * D];
    __shared__ float xs[32 * D];
    const int t = threadIdx.x;
    const int row0 = blockIdx.x * 32;
    const float4* Wv = (const float4*)W;
    float4* Wsv = (float4*)Ws;
#pragma unroll
    for (int i = 0; i < 16; ++i) Wsv[t + 256 * i] = Wv[t + 256 * i];
    const float4* xv = (const float4*)xin;
    float4* xsv = (float4*)xs;
#pragma unroll
    for (int i = 0; i < 4; ++i) {
        int f4 = t + 256 * i;
        int row = row0 + (f4 >> 5);
        if (row < n_rows) xsv[f4] = xv[(size_t)row0 * 32 + f4];
    }
    __syncthreads();
    const int cg = t & 31;
    const int rg = t >> 5;
    float4 bias = ((const float4*)b)[cg];
    float4 acc[4];
#pragma unroll
    for (int ri = 0; ri < 4; ++ri) acc[ri] = make_float4(0.f, 0.f, 0.f, 0.f);
#pragma unroll 4
    for (int k = 0; k < D; k += 4) {
        float4 w0 = Wsv[(k + 0) * 32 + cg];
        float4 w1 = Wsv[(k + 1) * 32 + cg];
        float4 w2 = Wsv[(k + 2) * 32 + cg];
        float4 w3 = Wsv[(k + 3) * 32 + cg];
#pragma unroll
        for (int ri = 0; ri < 4; ++ri) {
            float4 xa = xsv[(rg + 8 * ri) * 32 + (k >> 2)];
            acc[ri].x = fmaf(xa.x, w0.x, fmaf(xa.y, w1.x, fmaf(xa.z, w2.x, fmaf(xa.w, w3.x, acc[ri].x))));
            acc[ri].y = fmaf(xa.x, w0.y, fmaf(xa.y, w1.y, fmaf(xa.z, w2.y, fmaf(xa.w, w3.y, acc[ri].y))));
            acc[ri].z = fmaf(xa.x, w0.z, fmaf(xa.y, w1.z, fmaf(xa.z, w2.z, fmaf(xa.w, w3.z, acc[ri].z))));
            acc[ri].w = fmaf(xa.x, w0.w, fmaf(xa.y, w1.w, fmaf(xa.z, w2.w, fmaf(xa.w, w3.w, acc[ri].w))));
        }
    }
#pragma unroll
    for (int ri = 0; ri < 4; ++ri) {
        int row = row0 + rg + 8 * ri;
        if (row >= n_rows) continue;
        float4 o;
        o.x = acc[ri].x + bias.x; o.y = acc[ri].y + bias.y;
        o.z = acc[ri].z + bias.z; o.w = acc[ri].w + bias.w;
        if (RELU) {
            o.x = fmaxf(o.x, 0.f); o.y = fmaxf(o.y, 0.f);
            o.z = fmaxf(o.z, 0.f); o.w = fmaxf(o.w, 0.f);
        }
        ((float4*)xout)[(size_t)row * 32 + cg] = o;
    }
}

__global__ __launch_bounds__(256) void zero_kernel(float4* p, int n4)
{
    int i = blockIdx.x * 256 + threadIdx.x;
    int stride = gridDim.x * 256;
    for (; i < n4; i += stride) p[i] = make_float4(0.f, 0.f, 0.f, 0.f);
}

__global__ __launch_bounds__(256) void scatter_kernel(
    const float* __restrict__ h, const int* __restrict__ esrc,
    const int* __restrict__ edst, float* __restrict__ agg, long n_items)
{
    long idx = (long)blockIdx.x * 256 + threadIdx.x;
    long stride = (long)gridDim.x * 256;
    for (; idx < n_items; idx += stride) {
        int e = (int)(idx >> 7);
        int c = (int)(idx & 127);
        int s = esrc[e];
        int d = edst[e];
        unsafeAtomicAdd(&agg[(size_t)d * D + c], h[(size_t)s * D + c]);
    }
}

extern "C" void kernel_launch(void* const* d_in, const int* in_sizes, int n_in,
                              void* d_out, int out_size, void* d_ws, size_t ws_size,
                              hipStream_t stream)
{
    const float* x    = (const float*)d_in[0];
    const int*   esrc = (const int*)d_in[1];
    const int*   edst = (const int*)d_in[2];
    const float* W1   = (const float*)d_in[3];
    const float* b1   = (const float*)d_in[4];
    const float* W2   = (const float*)d_in[5];
    const float* b2   = (const float*)d_in[6];
    float* out = (float*)d_out;

    const int N = in_sizes[0] / D;   // 100000
    const int E = in_sizes[1];       // 1600000
    const int NB = (N + NPB - 1) / NPB;   // 391

    char* ws = (char*)d_ws;
    size_t off_z     = 0;                                        // z: 25.6 MB
    size_t off_pairs = off_z + (size_t)N * 256;
    size_t off_srcs  = off_pairs + (size_t)NBMAX * BKCAP * 4;    // 16.8 MB
    size_t off_noff  = off_srcs + (size_t)NBMAX * BKCAP * 4;     // 16.8 MB
    size_t off_gfill = (off_noff + (size_t)N * 8 + 255) & ~(size_t)255;
    size_t off_ovfc  = off_gfill + NBMAX * 4;
    size_t off_ovfl  = off_ovfc + 16;
    size_t off_pack  = (off_ovfl + (size_t)OVF_CAP * 8 + 255) & ~(size_t)255;
    size_t need      = off_pack + 65536;

    const int gchunk = (E + CHUNK - 1) / CHUNK;   // 196
    const int nblk128 = (N + 127) / 128;          // 782

    if (ws_size >= need && N <= NBMAX * NPB) {
        uint4*    z4    = (uint4*)(ws + off_z);
        unsigned* pairs = (unsigned*)(ws + off_pairs);
        int*      srcs  = (int*)(ws + off_srcs);
        int2*     noff2 = (int2*)(ws + off_noff);
        int*      gfill = (int*)(ws + off_gfill);
        int*      ovfc  = (int*)(ws + off_ovfc);
        int2*     ovfl  = (int2*)(ws + off_ovfl);
        uint4*    pack  = (uint4*)(ws + off_pack);

        // 0) pack weights; block 16 zeroes gfill+ovfc (NBMAX+4 ints)
        pack_w<<<17, 256, 0, stream>>>(W1, W2, pack, gfill, NBMAX + 4);

        // 1) FUSED: edge bucketing (196 blocks) + z=relu(x@W1+b1)@W2 (782)
        build_gemm<<<gchunk + nblk128, 256, 0, stream>>>(
            esrc, edst, gfill, pairs, ovfc, ovfl, E, NB, gchunk,
            x, pack, b1, z4, N);

        // 2) bucket pairs -> global CSR
        node_sort<<<NB, 256, 0, stream>>>(pairs, gfill, srcs, noff2, N);

        // 3) out[n] = sum z[src] + b2 (f32, 32-lane uint2 gather, 8-deep MLP)
        pull_csr<<<(N + 7) / 8, 256, 0, stream>>>(
            (const uint2*)z4, srcs, noff2, b2, out, N);

        // 4) overflow edges (normally zero)
        ovf_f32<<<8, 32, 0, stream>>>(ovfc, ovfl, (const uint2*)z4, out);
    } else {
        float* h = (float*)ws;
        const int nb32 = (N + 31) / 32;
        gemm_bias_act<true><<<nb32, 256, 0, stream>>>(x, W1, b1, h, N);
        zero_kernel<<<2048, 256, 0, stream>>>((float4*)out, N * D / 4);
        scatter_kernel<<<8192, 256, 0, stream>>>(h, esrc, edst, out, (long)E * D);
        gemm_bias_act<false><<<nb32, 256, 0, stream>>>(out, W2, b2, out, N);
    }
}